// Round 1
// baseline (1450.805 us; speedup 1.0000x reference)
//
#include <hip/hip_runtime.h>
#include <math.h>

#define Bn 4
#define Cc 96
#define Hh 48
#define Ww 48
#define HW 2304
#define Dd 192
#define NS 16
#define Kk 4
#define RK 6
#define CD 38   // RK + 2*NS
#define Ll 2304

__device__ __forceinline__ float sigmoidf_(float x){ return 1.0f/(1.0f+__expf(-x)); }
__device__ __forceinline__ float siluf_(float x){ return x*sigmoidf_(x); }
__device__ __forceinline__ float softplusf_(float x){ return (x>20.0f)? x : log1pf(__expf(x)); }

// ---- K1a: s[b,c] = mean over HW ----
__global__ __launch_bounds__(256) void k_mean(const float* __restrict__ x, float* __restrict__ s){
  int bc = blockIdx.x; // 0..B*C-1
  const float* p = x + (size_t)bc*HW;
  float acc = 0.f;
  for(int i=threadIdx.x;i<HW;i+=256) acc += p[i];
  __shared__ float red[256];
  red[threadIdx.x]=acc; __syncthreads();
  for(int o=128;o>0;o>>=1){ if(threadIdx.x<o) red[threadIdx.x]+=red[threadIdx.x+o]; __syncthreads(); }
  if(threadIdx.x==0) s[bc]=red[0]*(1.0f/HW);
}

// ---- K1b: a = sigmoid(relu(s@w1^T)@w2^T) ----
__global__ __launch_bounds__(384) void k_ca(const float* __restrict__ s, const float* __restrict__ w1,
                     const float* __restrict__ w2, float* __restrict__ a){
  __shared__ float hid[Bn*RK];
  int tid=threadIdx.x; // 384 threads
  if(tid<Bn*RK){
    int b=tid/RK, r=tid%RK;
    float acc=0.f;
    for(int c=0;c<Cc;c++) acc += s[b*Cc+c]*w1[r*Cc+c];
    hid[tid]=fmaxf(acc,0.f);
  }
  __syncthreads();
  int b=tid/Cc, c=tid%Cc;
  float acc=0.f;
  for(int r=0;r<RK;r++) acc += hid[b*RK+r]*w2[c*RK+r];
  a[tid]=sigmoidf_(acc);
}

// ---- K2: xi[b,pos,c] = x[b,c,pos]*a[b,c]  (tiled transpose) ----
__global__ __launch_bounds__(256) void k_xca(const float* __restrict__ x, const float* __restrict__ a,
                      float* __restrict__ xi){
  __shared__ float tile[32][65];
  int p0 = blockIdx.x*64, c0 = blockIdx.y*32, b = blockIdx.z;
  int pj = threadIdx.x%64, ci = threadIdx.x/64;
  for(int i=0;i<8;i++){
    int c = c0+ci+i*4;
    tile[ci+i*4][pj] = x[((size_t)(b*Cc+c))*HW + p0+pj]*a[b*Cc+c];
  }
  __syncthreads();
  int cl = threadIdx.x%32, pl = threadIdx.x/32;
  for(int i=0;i<8;i++){
    int p = pl + i*8;
    xi[((size_t)(b*HW + p0+p))*Cc + c0+cl] = tile[cl][p];
  }
}

// ---- K3: per-pixel LayerNorm(C=96) + in_proj (384x96) -> xc (B,HW,D), z (B,HW,D) ----
__global__ __launch_bounds__(256) void k_lnproj(const float* __restrict__ xi,
    const float* __restrict__ g, const float* __restrict__ bta,
    const float* __restrict__ w, float* __restrict__ xc, float* __restrict__ z){
  int pix = blockIdx.x;
  const float* row = xi + (size_t)pix*Cc;
  __shared__ float xn[Cc];
  __shared__ float sA[128], sB[128];
  __shared__ float mrs[2];
  int tid=threadIdx.x;
  float v = 0.f;
  if(tid<Cc) v = row[tid];
  if(tid<128){ sA[tid]=v; sB[tid]=v*v; }
  __syncthreads();
  for(int o=64;o>0;o>>=1){ if(tid<o){ sA[tid]+=sA[tid+o]; sB[tid]+=sB[tid+o]; } __syncthreads(); }
  if(tid==0){
    float mean = sA[0]*(1.0f/Cc);
    float var  = sB[0]*(1.0f/Cc) - mean*mean;
    mrs[0]=mean; mrs[1]=rsqrtf(var+1e-5f);
  }
  __syncthreads();
  if(tid<Cc) xn[tid] = (v-mrs[0])*mrs[1]*g[tid] + bta[tid];
  __syncthreads();
  for(int j=tid;j<2*Dd;j+=256){
    const float4* wr = (const float4*)(w + (size_t)j*Cc);
    float acc=0.f;
    #pragma unroll
    for(int c4=0;c4<Cc/4;c4++){
      float4 wv = wr[c4];
      acc += wv.x*xn[c4*4] + wv.y*xn[c4*4+1] + wv.z*xn[c4*4+2] + wv.w*xn[c4*4+3];
    }
    if(j<Dd) xc[(size_t)pix*Dd + j] = acc;
    else     z [(size_t)pix*Dd + j-Dd] = acc;
  }
}

// ---- K4: depthwise 3x3 conv SAME + bias + SiLU, channels-last ----
__global__ __launch_bounds__(256) void k_conv(const float* __restrict__ xc, const float* __restrict__ cw,
                       const float* __restrict__ cb, float* __restrict__ xo){
  int idx = blockIdx.x*256 + threadIdx.x; // B*HW*(D/4)
  if(idx >= Bn*HW*(Dd/4)) return;
  int d4 = idx % (Dd/4); int pos = (idx/(Dd/4))%HW; int b = idx/((Dd/4)*HW);
  int h = pos/Ww, w = pos%Ww;
  int d0 = d4*4;
  float4 acc = {cb[d0],cb[d0+1],cb[d0+2],cb[d0+3]};
  #pragma unroll
  for(int kh=0;kh<3;kh++){
    int hh=h+kh-1; if(hh<0||hh>=Hh) continue;
    #pragma unroll
    for(int kw=0;kw<3;kw++){
      int ww2=w+kw-1; if(ww2<0||ww2>=Ww) continue;
      float4 v = *(const float4*)(xc + ((size_t)(b*HW + hh*Ww+ww2))*Dd + d0);
      int wi = kh*3+kw;
      acc.x += v.x*cw[(d0+0)*9+wi];
      acc.y += v.y*cw[(d0+1)*9+wi];
      acc.z += v.z*cw[(d0+2)*9+wi];
      acc.w += v.w*cw[(d0+3)*9+wi];
    }
  }
  float4 o; o.x=siluf_(acc.x); o.y=siluf_(acc.y); o.z=siluf_(acc.z); o.w=siluf_(acc.w);
  *(float4*)(xo + ((size_t)(b*HW+pos))*Dd + d0) = o;
}

// ---- K5: x_dbl (38x192 matvec) + dt (192x6) per (b,k,t); 4 t's per block ----
__global__ __launch_bounds__(256) void k_xdbl(const float* __restrict__ xconv,
   const float* __restrict__ xpw, const float* __restrict__ dtw,
   const float* __restrict__ dtb, float* __restrict__ dtO,
   float* __restrict__ BsO, float* __restrict__ CsO){
  int blk = blockIdx.x;
  int t0 = (blk % (Ll/4))*4;
  int k  = (blk/(Ll/4))%Kk;
  int b  = blk/((Ll/4)*Kk);
  __shared__ float xsv[4][Dd];
  __shared__ float dts[4][RK];
  int tid=threadIdx.x;
  for(int i=tid;i<4*Dd;i+=256){
    int tt=i/Dd, d=i%Dd;
    int t=t0+tt;
    int tp = (k>=2)? (Ll-1-t) : t;
    int pos = (k&1)? ((tp%Ww)*Ww + tp/Ww) : tp;
    xsv[tt][d] = xconv[((size_t)(b*HW+pos))*Dd + d];
  }
  __syncthreads();
  if(tid < 4*CD){
    int tt=tid/CD, c=tid%CD;
    int t=t0+tt;
    const float4* wr = (const float4*)(xpw + ((size_t)(k*CD+c))*Dd);
    float acc=0.f;
    #pragma unroll
    for(int i=0;i<Dd/4;i++){
      float4 wv=wr[i];
      acc += wv.x*xsv[tt][i*4]+wv.y*xsv[tt][i*4+1]+wv.z*xsv[tt][i*4+2]+wv.w*xsv[tt][i*4+3];
    }
    if(c<RK) dts[tt][c]=acc;
    else if(c<RK+NS) BsO[(((size_t)(b*Kk+k))*Ll+t)*NS + (c-RK)] = acc;
    else             CsO[(((size_t)(b*Kk+k))*Ll+t)*NS + (c-RK-NS)] = acc;
  }
  __syncthreads();
  for(int i=tid;i<4*Dd;i+=256){
    int tt=i/Dd, d=i%Dd;
    float acc = dtb[k*Dd+d];
    #pragma unroll
    for(int r=0;r<RK;r++) acc += dtw[((size_t)(k*Dd+d))*RK + r]*dts[tt][r];
    dtO[(((size_t)(b*Kk+k))*Ll + (t0+tt))*Dd + d] = softplusf_(acc);
  }
}

// ---- K6: selective scan. lane-per-(d,n), 16-lane reduce. block = 16 d x 16 n ----
__global__ __launch_bounds__(256) void k_scan(const float* __restrict__ dtB,
  const float* __restrict__ BsB, const float* __restrict__ CsB,
  const float* __restrict__ xconv, const float* __restrict__ Alog,
  const float* __restrict__ Ds, float* __restrict__ yB){
  int blk=blockIdx.x;
  int dt16 = blk % (Dd/16);
  int k = (blk/(Dd/16))%Kk;
  int b = blk/((Dd/16)*Kk);
  int tid=threadIdx.x;
  int g = tid>>4, n = tid&15;
  int d = dt16*16 + g;
  float An = -__expf(Alog[((size_t)(k*Dd+d))*NS + n]);
  float Dv = Ds[k*Dd+d];
  const float* dtp = dtB + ((size_t)(b*Kk+k))*Ll*Dd + d;
  const float* Bp  = BsB + ((size_t)(b*Kk+k))*Ll*NS + n;
  const float* Cp  = CsB + ((size_t)(b*Kk+k))*Ll*NS + n;
  float*       yp  = yB  + ((size_t)(b*Kk+k))*Ll*Dd + d;
  const float* up  = xconv + (size_t)b*HW*Dd + d;
  float h = 0.f;
  for(int t=0;t<Ll;t++){
    int tp = (k>=2)? (Ll-1-t):t;
    int pos = (k&1)? ((tp%Ww)*Ww + tp/Ww) : tp;
    float dtv = dtp[t*Dd];
    float uv  = up[pos*Dd];
    float Bv  = Bp[t*NS];
    float Cv  = Cp[t*NS];
    float ae = __expf(dtv*An);
    h = h*ae + dtv*uv*Bv;
    float p = h*Cv;
    p += __shfl_xor(p,1); p += __shfl_xor(p,2); p += __shfl_xor(p,4); p += __shfl_xor(p,8);
    if(n==0) yp[t*Dd] = p + Dv*uv;
  }
}

// ---- K7: merge 4 directions + LN(D=192) + silu(z) gate + out_proj + residual -> (B,HW,C) ----
__global__ __launch_bounds__(256) void k_merge(const float* __restrict__ yB,
  const float* __restrict__ og, const float* __restrict__ ob,
  const float* __restrict__ zB, const float* __restrict__ opw,
  const float* __restrict__ xi, float* __restrict__ ot){
  int pix = blockIdx.x; int b = pix/HW; int pos = pix%HW;
  int h = pos/Ww, w = pos%Ww;
  int lwh = w*Hh + h;
  int tid = threadIdx.x;
  __shared__ float yv[Dd];
  __shared__ float sA[128], sB[128];
  __shared__ float mrs[2];
  float v=0.f;
  if(tid<Dd){
    size_t base = ((size_t)b*Kk)*Ll*Dd;
    v = yB[base + (size_t)(0*Ll + pos)*Dd + tid]
      + yB[base + (size_t)(2*Ll + (Ll-1-pos))*Dd + tid]
      + yB[base + (size_t)(1*Ll + lwh)*Dd + tid]
      + yB[base + (size_t)(3*Ll + (Ll-1-lwh))*Dd + tid];
  }
  if(tid<128){ sA[tid]=v; sB[tid]=v*v; }
  __syncthreads();
  if(tid>=128 && tid<Dd){ sA[tid-128]+=v; sB[tid-128]+=v*v; }
  __syncthreads();
  for(int o=64;o>0;o>>=1){ if(tid<o){ sA[tid]+=sA[tid+o]; sB[tid]+=sB[tid+o]; } __syncthreads(); }
  if(tid==0){
    float mean = sA[0]*(1.0f/Dd);
    float var  = sB[0]*(1.0f/Dd) - mean*mean;
    mrs[0]=mean; mrs[1]=rsqrtf(var+1e-5f);
  }
  __syncthreads();
  if(tid<Dd){
    float zv = zB[(size_t)pix*Dd + tid];
    float yn = (v-mrs[0])*mrs[1]*og[tid] + ob[tid];
    yv[tid] = yn * siluf_(zv);
  }
  __syncthreads();
  if(tid<Cc){
    const float4* wr = (const float4*)(opw + (size_t)tid*Dd);
    float acc=0.f;
    #pragma unroll
    for(int i=0;i<Dd/4;i++){
      float4 wv=wr[i];
      acc += wv.x*yv[i*4]+wv.y*yv[i*4+1]+wv.z*yv[i*4+2]+wv.w*yv[i*4+3];
    }
    ot[(size_t)pix*Cc + tid] = acc + xi[(size_t)pix*Cc + tid];
  }
}

// ---- K8: (B,HW,C) -> (B,C,HW) tiled transpose ----
__global__ __launch_bounds__(256) void k_outT(const float* __restrict__ ot, float* __restrict__ out){
  __shared__ float tile[64][33];
  int p0=blockIdx.x*64, c0=blockIdx.y*32, b=blockIdx.z;
  int cl=threadIdx.x%32, pl=threadIdx.x/32;
  for(int i=0;i<8;i++){
    int p = pl+i*8;
    tile[p][cl] = ot[((size_t)(b*HW+p0+p))*Cc + c0+cl];
  }
  __syncthreads();
  int pj=threadIdx.x%64, ci=threadIdx.x/64;
  for(int i=0;i<8;i++){
    int c=ci+i*4;
    out[((size_t)(b*Cc+c0+c))*HW + p0+pj] = tile[pj][c];
  }
}

extern "C" void kernel_launch(void* const* d_in, const int* in_sizes, int n_in,
                              void* d_out, int out_size, void* d_ws, size_t ws_size,
                              hipStream_t stream){
  const float* x   = (const float*)d_in[0];
  const float* cw1 = (const float*)d_in[1];
  const float* cw2 = (const float*)d_in[2];
  const float* lng = (const float*)d_in[3];
  const float* lnb = (const float*)d_in[4];
  const float* ipw = (const float*)d_in[5];
  const float* cvw = (const float*)d_in[6];
  const float* cvb = (const float*)d_in[7];
  const float* xpw = (const float*)d_in[8];
  const float* dtw = (const float*)d_in[9];
  const float* dtb = (const float*)d_in[10];
  const float* alg = (const float*)d_in[11];
  const float* ds  = (const float*)d_in[12];
  const float* ong = (const float*)d_in[13];
  const float* onb = (const float*)d_in[14];
  const float* opw = (const float*)d_in[15];
  float* out = (float*)d_out;
  float* ws = (float*)d_ws;

  float* s_   = ws;                 // 384
  float* a_   = s_  + 384;          // 384
  float* xi_  = a_  + 384;          // 884736
  float* xc_  = xi_ + 884736;       // 1769472
  float* z_   = xc_ + 1769472;      // 1769472
  float* xo_  = z_  + 1769472;      // 1769472
  float* dt_  = xo_ + 1769472;      // 7077888
  float* Bs_  = dt_ + 7077888;      // 589824
  float* Cs_  = Bs_ + 589824;       // 589824
  float* yb_  = Cs_ + 589824;       // 7077888
  float* ot_  = yb_ + 7077888;      // 884736

  k_mean  <<<Bn*Cc, 256, 0, stream>>>(x, s_);
  k_ca    <<<1, 384, 0, stream>>>(s_, cw1, cw2, a_);
  k_xca   <<<dim3(HW/64, Cc/32, Bn), 256, 0, stream>>>(x, a_, xi_);
  k_lnproj<<<Bn*HW, 256, 0, stream>>>(xi_, lng, lnb, ipw, xc_, z_);
  k_conv  <<<(Bn*HW*(Dd/4))/256, 256, 0, stream>>>(xc_, cvw, cvb, xo_);
  k_xdbl  <<<Bn*Kk*(Ll/4), 256, 0, stream>>>(xo_, xpw, dtw, dtb, dt_, Bs_, Cs_);
  k_scan  <<<Bn*Kk*(Dd/16), 256, 0, stream>>>(dt_, Bs_, Cs_, xo_, alg, ds, yb_);
  k_merge <<<Bn*HW, 256, 0, stream>>>(yb_, ong, onb, z_, opw, xi_, ot_);
  k_outT  <<<dim3(HW/64, Cc/32, Bn), 256, 0, stream>>>(ot_, out);
}

// Round 2
// 631.827 us; speedup vs baseline: 2.2962x; 2.2962x over previous
//
#include <hip/hip_runtime.h>
#include <math.h>

#define Bn 4
#define Cc 96
#define Hh 48
#define Ww 48
#define HW 2304
#define Dd 192
#define NS 16
#define Kk 4
#define RK 6
#define CD 38   // RK + 2*NS
#define Ll 2304
#define NCH 16
#define CL 144  // Ll / NCH

typedef _Float16 half4 __attribute__((ext_vector_type(4)));

__device__ __forceinline__ float sigmoidf_(float x){ return 1.0f/(1.0f+__expf(-x)); }
__device__ __forceinline__ float siluf_(float x){ return x*sigmoidf_(x); }
__device__ __forceinline__ float softplusf_(float x){ return (x>20.0f)? x : log1pf(__expf(x)); }

// ---- K1a: s[b,c] = mean over HW ----
__global__ __launch_bounds__(256) void k_mean(const float* __restrict__ x, float* __restrict__ s){
  int bc = blockIdx.x;
  const float* p = x + (size_t)bc*HW;
  float acc = 0.f;
  for(int i=threadIdx.x;i<HW;i+=256) acc += p[i];
  __shared__ float red[256];
  red[threadIdx.x]=acc; __syncthreads();
  for(int o=128;o>0;o>>=1){ if(threadIdx.x<o) red[threadIdx.x]+=red[threadIdx.x+o]; __syncthreads(); }
  if(threadIdx.x==0) s[bc]=red[0]*(1.0f/HW);
}

// ---- K1b: a = sigmoid(relu(s@w1^T)@w2^T) ----
__global__ __launch_bounds__(384) void k_ca(const float* __restrict__ s, const float* __restrict__ w1,
                     const float* __restrict__ w2, float* __restrict__ a){
  __shared__ float hid[Bn*RK];
  int tid=threadIdx.x;
  if(tid<Bn*RK){
    int b=tid/RK, r=tid%RK;
    float acc=0.f;
    for(int c=0;c<Cc;c++) acc += s[b*Cc+c]*w1[r*Cc+c];
    hid[tid]=fmaxf(acc,0.f);
  }
  __syncthreads();
  int b=tid/Cc, c=tid%Cc;
  float acc=0.f;
  for(int r=0;r<RK;r++) acc += hid[b*RK+r]*w2[c*RK+r];
  a[tid]=sigmoidf_(acc);
}

// ---- K2: xi[b,pos,c] = x[b,c,pos]*a[b,c]  (tiled transpose) ----
__global__ __launch_bounds__(256) void k_xca(const float* __restrict__ x, const float* __restrict__ a,
                      float* __restrict__ xi){
  __shared__ float tile[32][65];
  int p0 = blockIdx.x*64, c0 = blockIdx.y*32, b = blockIdx.z;
  int pj = threadIdx.x%64, ci = threadIdx.x/64;
  for(int i=0;i<8;i++){
    int c = c0+ci+i*4;
    tile[ci+i*4][pj] = x[((size_t)(b*Cc+c))*HW + p0+pj]*a[b*Cc+c];
  }
  __syncthreads();
  int cl = threadIdx.x%32, pl = threadIdx.x/32;
  for(int i=0;i<8;i++){
    int p = pl + i*8;
    xi[((size_t)(b*HW + p0+p))*Cc + c0+cl] = tile[cl][p];
  }
}

// ---- K3: per-pixel LayerNorm(C=96) + in_proj -> xc, z ----
__global__ __launch_bounds__(256) void k_lnproj(const float* __restrict__ xi,
    const float* __restrict__ g, const float* __restrict__ bta,
    const float* __restrict__ w, float* __restrict__ xc, float* __restrict__ z){
  int pix = blockIdx.x;
  const float* row = xi + (size_t)pix*Cc;
  __shared__ float xn[Cc];
  __shared__ float sA[128], sB[128];
  __shared__ float mrs[2];
  int tid=threadIdx.x;
  float v = 0.f;
  if(tid<Cc) v = row[tid];
  if(tid<128){ sA[tid]=v; sB[tid]=v*v; }
  __syncthreads();
  for(int o=64;o>0;o>>=1){ if(tid<o){ sA[tid]+=sA[tid+o]; sB[tid]+=sB[tid+o]; } __syncthreads(); }
  if(tid==0){
    float mean = sA[0]*(1.0f/Cc);
    float var  = sB[0]*(1.0f/Cc) - mean*mean;
    mrs[0]=mean; mrs[1]=rsqrtf(var+1e-5f);
  }
  __syncthreads();
  if(tid<Cc) xn[tid] = (v-mrs[0])*mrs[1]*g[tid] + bta[tid];
  __syncthreads();
  for(int j=tid;j<2*Dd;j+=256){
    const float4* wr = (const float4*)(w + (size_t)j*Cc);
    float acc=0.f;
    #pragma unroll
    for(int c4=0;c4<Cc/4;c4++){
      float4 wv = wr[c4];
      acc += wv.x*xn[c4*4] + wv.y*xn[c4*4+1] + wv.z*xn[c4*4+2] + wv.w*xn[c4*4+3];
    }
    if(j<Dd) xc[(size_t)pix*Dd + j] = acc;
    else     z [(size_t)pix*Dd + j-Dd] = acc;
  }
}

// ---- K4: depthwise 3x3 conv SAME + bias + SiLU ----
__global__ __launch_bounds__(256) void k_conv(const float* __restrict__ xc, const float* __restrict__ cw,
                       const float* __restrict__ cb, float* __restrict__ xo){
  int idx = blockIdx.x*256 + threadIdx.x;
  if(idx >= Bn*HW*(Dd/4)) return;
  int d4 = idx % (Dd/4); int pos = (idx/(Dd/4))%HW; int b = idx/((Dd/4)*HW);
  int h = pos/Ww, w = pos%Ww;
  int d0 = d4*4;
  float4 acc = {cb[d0],cb[d0+1],cb[d0+2],cb[d0+3]};
  #pragma unroll
  for(int kh=0;kh<3;kh++){
    int hh=h+kh-1; if(hh<0||hh>=Hh) continue;
    #pragma unroll
    for(int kw=0;kw<3;kw++){
      int ww2=w+kw-1; if(ww2<0||ww2>=Ww) continue;
      float4 v = *(const float4*)(xc + ((size_t)(b*HW + hh*Ww+ww2))*Dd + d0);
      int wi = kh*3+kw;
      acc.x += v.x*cw[(d0+0)*9+wi];
      acc.y += v.y*cw[(d0+1)*9+wi];
      acc.z += v.z*cw[(d0+2)*9+wi];
      acc.w += v.w*cw[(d0+3)*9+wi];
    }
  }
  float4 o; o.x=siluf_(acc.x); o.y=siluf_(acc.y); o.z=siluf_(acc.z); o.w=siluf_(acc.w);
  *(float4*)(xo + ((size_t)(b*HW+pos))*Dd + d0) = o;
}

// ---- K5: x_dbl + dt per (b,k,t0..t0+3); writes scan-order transposed streams ----
__global__ __launch_bounds__(256) void k_xdbl(const float* __restrict__ xconv,
   const float* __restrict__ xpw, const float* __restrict__ dtw,
   const float* __restrict__ dtb, _Float16* __restrict__ dtT,
   _Float16* __restrict__ uT, float* __restrict__ BT, float* __restrict__ CT){
  int blk = blockIdx.x;
  int t0 = (blk % (Ll/4))*4;
  int k  = (blk/(Ll/4))%Kk;
  int b  = blk/((Ll/4)*Kk);
  __shared__ float xsv[4][Dd];
  __shared__ float sdt[4][Dd];
  __shared__ float dts[4][RK];
  __shared__ float sB[4][NS];
  __shared__ float sC[4][NS];
  int tid=threadIdx.x;
  for(int i=tid;i<4*Dd;i+=256){
    int tt=i/Dd, d=i%Dd;
    int t=t0+tt;
    int tp = (k>=2)? (Ll-1-t) : t;
    int pos = (k&1)? ((tp%Ww)*Ww + tp/Ww) : tp;
    xsv[tt][d] = xconv[((size_t)(b*HW+pos))*Dd + d];
  }
  __syncthreads();
  if(tid < 4*CD){
    int tt=tid/CD, c=tid%CD;
    const float4* wr = (const float4*)(xpw + ((size_t)(k*CD+c))*Dd);
    float acc=0.f;
    #pragma unroll
    for(int i=0;i<Dd/4;i++){
      float4 wv=wr[i];
      acc += wv.x*xsv[tt][i*4]+wv.y*xsv[tt][i*4+1]+wv.z*xsv[tt][i*4+2]+wv.w*xsv[tt][i*4+3];
    }
    if(c<RK) dts[tt][c]=acc;
    else if(c<RK+NS) sB[tt][c-RK]=acc;
    else             sC[tt][c-RK-NS]=acc;
  }
  __syncthreads();
  for(int i=tid;i<4*Dd;i+=256){
    int tt=i/Dd, d=i%Dd;
    float acc = dtb[k*Dd+d];
    #pragma unroll
    for(int r=0;r<RK;r++) acc += dtw[((size_t)(k*Dd+d))*RK + r]*dts[tt][r];
    sdt[tt][d] = softplusf_(acc);
  }
  __syncthreads();
  if(tid < Dd){
    half4 dv;
    dv[0]=(_Float16)sdt[0][tid]; dv[1]=(_Float16)sdt[1][tid];
    dv[2]=(_Float16)sdt[2][tid]; dv[3]=(_Float16)sdt[3][tid];
    *(half4*)(dtT + ((size_t)(b*Kk+k)*Dd + tid)*Ll + t0) = dv;
    if(k<2){
      half4 uv;
      uv[0]=(_Float16)xsv[0][tid]; uv[1]=(_Float16)xsv[1][tid];
      uv[2]=(_Float16)xsv[2][tid]; uv[3]=(_Float16)xsv[3][tid];
      *(half4*)(uT + ((size_t)(b*2+k)*Dd + tid)*Ll + t0) = uv;
    }
  } else if(tid < Dd+NS){
    int n = tid-Dd;
    float4 bv = {sB[0][n],sB[1][n],sB[2][n],sB[3][n]};
    *(float4*)(BT + ((size_t)(b*Kk+k)*NS + n)*Ll + t0) = bv;
  } else if(tid < Dd+2*NS){
    int n = tid-Dd-NS;
    float4 cv = {sC[0][n],sC[1][n],sC[2][n],sC[3][n]};
    *(float4*)(CT + ((size_t)(b*Kk+k)*NS + n)*Ll + t0) = cv;
  }
}

// ---- K6a: pass1 — per-chunk local scan: hloc + decay product ----
__global__ __launch_bounds__(256) void k_scan1(const _Float16* __restrict__ dtT,
  const _Float16* __restrict__ uT, const float* __restrict__ BT,
  const float* __restrict__ Alog, float* __restrict__ hloc, float* __restrict__ Pb){
  int blk=blockIdx.x;
  int d16 = blk % (Dd/16);
  int ch  = (blk/(Dd/16))%NCH;
  int k   = (blk/((Dd/16)*NCH))%Kk;
  int b   = blk/((Dd/16)*NCH*Kk);
  int tid=threadIdx.x;
  int g = tid>>4, n = tid&15;
  int d = d16*16 + g;
  float An = -__expf(Alog[((size_t)(k*Dd+d))*NS + n]);
  const _Float16* dp = dtT + ((size_t)(b*Kk+k)*Dd + d)*Ll + ch*CL;
  const _Float16* ub = uT  + ((size_t)(b*2+(k&1))*Dd + d)*Ll;
  const float*    Bp = BT  + ((size_t)(b*Kk+k)*NS + n)*Ll + ch*CL;
  bool rev = (k>=2);
  int s0 = ch*CL;
  float h=0.f, sdt=0.f;
  for(int tl=0; tl<CL; tl+=4){
    half4 dt4 = *(const half4*)(dp+tl);
    float4 B4 = *(const float4*)(Bp+tl);
    float u[4];
    if(!rev){
      half4 u4 = *(const half4*)(ub + s0+tl);
      u[0]=(float)u4[0]; u[1]=(float)u4[1]; u[2]=(float)u4[2]; u[3]=(float)u4[3];
    } else {
      half4 u4 = *(const half4*)(ub + (Ll-4-s0-tl));
      u[0]=(float)u4[3]; u[1]=(float)u4[2]; u[2]=(float)u4[1]; u[3]=(float)u4[0];
    }
    float Ba[4] = {B4.x,B4.y,B4.z,B4.w};
    #pragma unroll
    for(int j=0;j<4;j++){
      float dtv = (float)dt4[j];
      sdt += dtv;
      float ae = __expf(dtv*An);
      h = h*ae + dtv*u[j]*Ba[j];
    }
  }
  size_t o = (((size_t)(b*Kk+k)*NCH + ch)*Dd + d)*NS + n;
  hloc[o] = h;
  Pb[o]   = __expf(An*sdt);
}

// ---- K6b: combine — sequential over 16 chunks per (b,k,d,n) ----
__global__ __launch_bounds__(256) void k_comb(const float* __restrict__ hloc,
  const float* __restrict__ Pb, float* __restrict__ Hin){
  int idx = blockIdx.x*256 + threadIdx.x;   // B*K*D*NS = 49152
  int inner = idx % (Dd*NS);
  int bk = idx / (Dd*NS);
  size_t base = (size_t)bk*NCH*Dd*NS + inner;
  float H = 0.f;
  for(int ch=0; ch<NCH; ch++){
    size_t o = base + (size_t)ch*Dd*NS;
    Hin[o] = H;
    H = Pb[o]*H + hloc[o];
  }
}

// ---- K6c: pass2 — scan chunk from true init state, write y ----
__global__ __launch_bounds__(256) void k_scan2(const _Float16* __restrict__ dtT,
  const _Float16* __restrict__ uT, const float* __restrict__ BT,
  const float* __restrict__ CT, const float* __restrict__ Alog,
  const float* __restrict__ Ds, const float* __restrict__ Hin,
  float* __restrict__ yB){
  int blk=blockIdx.x;
  int d16 = blk % (Dd/16);
  int ch  = (blk/(Dd/16))%NCH;
  int k   = (blk/((Dd/16)*NCH))%Kk;
  int b   = blk/((Dd/16)*NCH*Kk);
  int tid=threadIdx.x;
  int g = tid>>4, n = tid&15;
  int d = d16*16 + g;
  float An = -__expf(Alog[((size_t)(k*Dd+d))*NS + n]);
  float Dv = Ds[k*Dd+d];
  const _Float16* dp = dtT + ((size_t)(b*Kk+k)*Dd + d)*Ll + ch*CL;
  const _Float16* ub = uT  + ((size_t)(b*2+(k&1))*Dd + d)*Ll;
  const float*    Bp = BT  + ((size_t)(b*Kk+k)*NS + n)*Ll + ch*CL;
  const float*    Cp = CT  + ((size_t)(b*Kk+k)*NS + n)*Ll + ch*CL;
  float*          yp = yB  + ((size_t)(b*Kk+k)*Ll)*Dd + d;
  bool rev = (k>=2);
  int s0 = ch*CL;
  float h = Hin[(((size_t)(b*Kk+k)*NCH + ch)*Dd + d)*NS + n];
  for(int tl=0; tl<CL; tl+=4){
    half4 dt4 = *(const half4*)(dp+tl);
    float4 B4 = *(const float4*)(Bp+tl);
    float4 C4 = *(const float4*)(Cp+tl);
    float u[4];
    if(!rev){
      half4 u4 = *(const half4*)(ub + s0+tl);
      u[0]=(float)u4[0]; u[1]=(float)u4[1]; u[2]=(float)u4[2]; u[3]=(float)u4[3];
    } else {
      half4 u4 = *(const half4*)(ub + (Ll-4-s0-tl));
      u[0]=(float)u4[3]; u[1]=(float)u4[2]; u[2]=(float)u4[1]; u[3]=(float)u4[0];
    }
    float Ba[4] = {B4.x,B4.y,B4.z,B4.w};
    float Ca[4] = {C4.x,C4.y,C4.z,C4.w};
    float yv[4];
    #pragma unroll
    for(int j=0;j<4;j++){
      float dtv = (float)dt4[j];
      float ae = __expf(dtv*An);
      h = h*ae + dtv*u[j]*Ba[j];
      float p = h*Ca[j];
      p += __shfl_xor(p,1); p += __shfl_xor(p,2); p += __shfl_xor(p,4); p += __shfl_xor(p,8);
      yv[j] = p + Dv*u[j];
    }
    if(n==0){
      yp[(size_t)(s0+tl+0)*Dd] = yv[0];
      yp[(size_t)(s0+tl+1)*Dd] = yv[1];
      yp[(size_t)(s0+tl+2)*Dd] = yv[2];
      yp[(size_t)(s0+tl+3)*Dd] = yv[3];
    }
  }
}

// ---- K7: merge 4 directions + LN(D) + silu(z) gate + out_proj + residual ----
__global__ __launch_bounds__(256) void k_merge(const float* __restrict__ yB,
  const float* __restrict__ og, const float* __restrict__ ob,
  const float* __restrict__ zB, const float* __restrict__ opw,
  const float* __restrict__ xi, float* __restrict__ ot){
  int pix = blockIdx.x; int b = pix/HW; int pos = pix%HW;
  int h = pos/Ww, w = pos%Ww;
  int lwh = w*Hh + h;
  int tid = threadIdx.x;
  __shared__ float yv[Dd];
  __shared__ float sA[128], sB[128];
  __shared__ float mrs[2];
  float v=0.f;
  if(tid<Dd){
    size_t base = ((size_t)b*Kk)*Ll*Dd;
    v = yB[base + (size_t)(0*Ll + pos)*Dd + tid]
      + yB[base + (size_t)(2*Ll + (Ll-1-pos))*Dd + tid]
      + yB[base + (size_t)(1*Ll + lwh)*Dd + tid]
      + yB[base + (size_t)(3*Ll + (Ll-1-lwh))*Dd + tid];
  }
  if(tid<128){ sA[tid]=v; sB[tid]=v*v; }
  __syncthreads();
  if(tid>=128 && tid<Dd){ sA[tid-128]+=v; sB[tid-128]+=v*v; }
  __syncthreads();
  for(int o=64;o>0;o>>=1){ if(tid<o){ sA[tid]+=sA[tid+o]; sB[tid]+=sB[tid+o]; } __syncthreads(); }
  if(tid==0){
    float mean = sA[0]*(1.0f/Dd);
    float var  = sB[0]*(1.0f/Dd) - mean*mean;
    mrs[0]=mean; mrs[1]=rsqrtf(var+1e-5f);
  }
  __syncthreads();
  if(tid<Dd){
    float zv = zB[(size_t)pix*Dd + tid];
    float yn = (v-mrs[0])*mrs[1]*og[tid] + ob[tid];
    yv[tid] = yn * siluf_(zv);
  }
  __syncthreads();
  if(tid<Cc){
    const float4* wr = (const float4*)(opw + (size_t)tid*Dd);
    float acc=0.f;
    #pragma unroll
    for(int i=0;i<Dd/4;i++){
      float4 wv=wr[i];
      acc += wv.x*yv[i*4]+wv.y*yv[i*4+1]+wv.z*yv[i*4+2]+wv.w*yv[i*4+3];
    }
    ot[(size_t)pix*Cc + tid] = acc + xi[(size_t)pix*Cc + tid];
  }
}

// ---- K8: (B,HW,C) -> (B,C,HW) tiled transpose ----
__global__ __launch_bounds__(256) void k_outT(const float* __restrict__ ot, float* __restrict__ out){
  __shared__ float tile[64][33];
  int p0=blockIdx.x*64, c0=blockIdx.y*32, b=blockIdx.z;
  int cl=threadIdx.x%32, pl=threadIdx.x/32;
  for(int i=0;i<8;i++){
    int p = pl+i*8;
    tile[p][cl] = ot[((size_t)(b*HW+p0+p))*Cc + c0+cl];
  }
  __syncthreads();
  int pj=threadIdx.x%64, ci=threadIdx.x/64;
  for(int i=0;i<8;i++){
    int c=ci+i*4;
    out[((size_t)(b*Cc+c0+c))*HW + p0+pj] = tile[pj][c];
  }
}

extern "C" void kernel_launch(void* const* d_in, const int* in_sizes, int n_in,
                              void* d_out, int out_size, void* d_ws, size_t ws_size,
                              hipStream_t stream){
  const float* x   = (const float*)d_in[0];
  const float* cw1 = (const float*)d_in[1];
  const float* cw2 = (const float*)d_in[2];
  const float* lng = (const float*)d_in[3];
  const float* lnb = (const float*)d_in[4];
  const float* ipw = (const float*)d_in[5];
  const float* cvw = (const float*)d_in[6];
  const float* cvb = (const float*)d_in[7];
  const float* xpw = (const float*)d_in[8];
  const float* dtw = (const float*)d_in[9];
  const float* dtb = (const float*)d_in[10];
  const float* alg = (const float*)d_in[11];
  const float* ds  = (const float*)d_in[12];
  const float* ong = (const float*)d_in[13];
  const float* onb = (const float*)d_in[14];
  const float* opw = (const float*)d_in[15];
  float* out = (float*)d_out;
  float* ws = (float*)d_ws;

  float* s_   = ws;                          // 384
  float* a_   = s_  + 384;                   // 384
  float* xi_  = a_  + 384;                   // 884736
  float* xc_  = xi_ + 884736;                // 1769472 (reused: hloc+P after conv)
  float* z_   = xc_ + 1769472;               // 1769472
  float* xo_  = z_  + 1769472;               // 1769472
  _Float16* dtT_ = (_Float16*)(xo_ + 1769472);   // 7077888 halves
  _Float16* uT_  = dtT_ + 7077888;               // 3538944 halves
  float* BT_  = (float*)(uT_ + 3538944);     // 589824
  float* CT_  = BT_ + 589824;                // 589824
  float* yB_  = CT_ + 589824;                // 7077888
  float* ot_  = yB_ + 7077888;               // 884736 (reused: Hinit before merge)

  float* hloc_ = xc_;                        // 786432
  float* Pb_   = xc_ + 786432;               // 786432
  float* Hin_  = ot_;                        // 786432

  k_mean  <<<Bn*Cc, 256, 0, stream>>>(x, s_);
  k_ca    <<<1, 384, 0, stream>>>(s_, cw1, cw2, a_);
  k_xca   <<<dim3(HW/64, Cc/32, Bn), 256, 0, stream>>>(x, a_, xi_);
  k_lnproj<<<Bn*HW, 256, 0, stream>>>(xi_, lng, lnb, ipw, xc_, z_);
  k_conv  <<<(Bn*HW*(Dd/4))/256, 256, 0, stream>>>(xc_, cvw, cvb, xo_);
  k_xdbl  <<<Bn*Kk*(Ll/4), 256, 0, stream>>>(xo_, xpw, dtw, dtb, dtT_, uT_, BT_, CT_);
  k_scan1 <<<Bn*Kk*NCH*(Dd/16), 256, 0, stream>>>(dtT_, uT_, BT_, alg, hloc_, Pb_);
  k_comb  <<<(Bn*Kk*Dd*NS)/256, 256, 0, stream>>>(hloc_, Pb_, Hin_);
  k_scan2 <<<Bn*Kk*NCH*(Dd/16), 256, 0, stream>>>(dtT_, uT_, BT_, CT_, alg, ds, Hin_, yB_);
  k_merge <<<Bn*HW, 256, 0, stream>>>(yB_, ong, onb, z_, opw, xi_, ot_);
  k_outT  <<<dim3(HW/64, Cc/32, Bn), 256, 0, stream>>>(ot_, out);
}

// Round 3
// 436.480 us; speedup vs baseline: 3.3239x; 1.4476x over previous
//
#include <hip/hip_runtime.h>
#include <math.h>

#define Bn 4
#define Cc 96
#define Hh 48
#define Ww 48
#define HW 2304
#define Dd 192
#define NS 16
#define Kk 4
#define RK 6
#define CD 38   // RK + 2*NS
#define Ll 2304
#define NCH 16
#define CL 144  // Ll / NCH

typedef _Float16 half4 __attribute__((ext_vector_type(4)));

#define FMA4(A,W,U) { A.x=fmaf(W,U.x,A.x); A.y=fmaf(W,U.y,A.y); A.z=fmaf(W,U.z,A.z); A.w=fmaf(W,U.w,A.w); }

__device__ __forceinline__ float sigmoidf_(float x){ return 1.0f/(1.0f+__expf(-x)); }
__device__ __forceinline__ float siluf_(float x){ return x*sigmoidf_(x); }
__device__ __forceinline__ float softplusf_(float x){ return (x>20.0f)? x : log1pf(__expf(x)); }

// ---- K1a: s[b,c] = mean over HW ----
__global__ __launch_bounds__(256) void k_mean(const float* __restrict__ x, float* __restrict__ s){
  int bc = blockIdx.x;
  const float* p = x + (size_t)bc*HW;
  float acc = 0.f;
  for(int i=threadIdx.x;i<HW;i+=256) acc += p[i];
  __shared__ float red[256];
  red[threadIdx.x]=acc; __syncthreads();
  for(int o=128;o>0;o>>=1){ if(threadIdx.x<o) red[threadIdx.x]+=red[threadIdx.x+o]; __syncthreads(); }
  if(threadIdx.x==0) s[bc]=red[0]*(1.0f/HW);
}

// ---- K1b: a = sigmoid(relu(s@w1^T)@w2^T) ----
__global__ __launch_bounds__(384) void k_ca(const float* __restrict__ s, const float* __restrict__ w1,
                     const float* __restrict__ w2, float* __restrict__ a){
  __shared__ float hid[Bn*RK];
  int tid=threadIdx.x;
  if(tid<Bn*RK){
    int b=tid/RK, r=tid%RK;
    float acc=0.f;
    for(int c=0;c<Cc;c++) acc += s[b*Cc+c]*w1[r*Cc+c];
    hid[tid]=fmaxf(acc,0.f);
  }
  __syncthreads();
  int b=tid/Cc, c=tid%Cc;
  float acc=0.f;
  for(int r=0;r<RK;r++) acc += hid[b*RK+r]*w2[c*RK+r];
  a[tid]=sigmoidf_(acc);
}

// ---- K2: xi[b,pos,c] = x[b,c,pos]*a[b,c]  (tiled transpose) ----
__global__ __launch_bounds__(256) void k_xca(const float* __restrict__ x, const float* __restrict__ a,
                      float* __restrict__ xi){
  __shared__ float tile[32][65];
  int p0 = blockIdx.x*64, c0 = blockIdx.y*32, b = blockIdx.z;
  int pj = threadIdx.x%64, ci = threadIdx.x/64;
  for(int i=0;i<8;i++){
    int c = c0+ci+i*4;
    tile[ci+i*4][pj] = x[((size_t)(b*Cc+c))*HW + p0+pj]*a[b*Cc+c];
  }
  __syncthreads();
  int cl = threadIdx.x%32, pl = threadIdx.x/32;
  for(int i=0;i<8;i++){
    int p = pl + i*8;
    xi[((size_t)(b*HW + p0+p))*Cc + c0+cl] = tile[cl][p];
  }
}

// ---- K3: 32-px tile: LN(96) + in_proj GEMM -> xc, z ----
__global__ __launch_bounds__(256) void k_lnproj(const float* __restrict__ xi,
    const float* __restrict__ g, const float* __restrict__ bta,
    const float* __restrict__ w, float* __restrict__ xc, float* __restrict__ z){
  __shared__ float su[Cc*36];     // t-minor swizzled
  __shared__ float wl[128*97];
  int tid = threadIdx.x;
  int pix0 = blockIdx.x*32;
  // load + transpose (swizzled)
  #pragma unroll
  for(int i=0;i<3;i++){
    int f4 = tid + 256*i;               // 768 = 32px * 24
    int px = f4/24, c4 = f4%24;
    float4 v = *(const float4*)(xi + (size_t)(pix0+px)*Cc + 4*c4);
    int sw = 4*(c4&7);
    su[(4*c4+0)*36 + (px^sw)] = v.x;
    su[(4*c4+1)*36 + (px^sw)] = v.y;
    su[(4*c4+2)*36 + (px^sw)] = v.z;
    su[(4*c4+3)*36 + (px^sw)] = v.w;
  }
  __syncthreads();
  // LN per pixel: 8 lanes per px
  {
    int px = tid>>3, gg = tid&7;
    float sm=0.f, sq=0.f;
    float vals[12];
    #pragma unroll
    for(int i=0;i<12;i++){
      int d = gg + 8*i;
      float v = su[d*36 + (px ^ (4*((d>>2)&7)))];
      vals[i]=v; sm+=v; sq+=v*v;
    }
    sm += __shfl_xor(sm,1); sq += __shfl_xor(sq,1);
    sm += __shfl_xor(sm,2); sq += __shfl_xor(sq,2);
    sm += __shfl_xor(sm,4); sq += __shfl_xor(sq,4);
    float mean = sm*(1.0f/Cc);
    float var  = sq*(1.0f/Cc) - mean*mean;
    float rs = rsqrtf(var + 1e-5f);
    #pragma unroll
    for(int i=0;i<12;i++){
      int d = gg + 8*i;
      su[d*36 + (px ^ (4*((d>>2)&7)))] = (vals[i]-mean)*rs*g[d] + bta[d];
    }
  }
  __syncthreads();
  int t4 = tid&7, cg = tid>>3;
  for(int p=0;p<3;p++){
    if(p) __syncthreads();
    // stage 128 weight rows
    #pragma unroll
    for(int i=0;i<12;i++){
      int f4 = tid + 256*i;             // 3072 = 128*24
      int r = f4/24, c4 = f4%24;
      *(float4*)(wl + r*97 + 4*c4) = *(const float4*)(w + (size_t)(128*p + r)*Cc + 4*c4);
    }
    __syncthreads();
    float4 a0={0,0,0,0},a1={0,0,0,0},a2={0,0,0,0},a3={0,0,0,0};
    for(int d=0; d<Cc; d++){
      float4 u4 = *(const float4*)(su + d*36 + 4*(t4 ^ ((d>>2)&7)));
      float w0 = wl[(cg+  0)*97 + d];
      float w1 = wl[(cg+ 32)*97 + d];
      float w2 = wl[(cg+ 64)*97 + d];
      float w3 = wl[(cg+ 96)*97 + d];
      FMA4(a0,w0,u4); FMA4(a1,w1,u4); FMA4(a2,w2,u4); FMA4(a3,w3,u4);
    }
    #pragma unroll
    for(int j=0;j<4;j++){
      int c = 128*p + cg + 32*j;
      float4 a = (j==0)?a0:(j==1)?a1:(j==2)?a2:a3;
      #pragma unroll
      for(int q=0;q<4;q++){
        int px = pix0 + 4*t4 + q;
        float vv = (q==0)?a.x:(q==1)?a.y:(q==2)?a.z:a.w;
        if(c < Dd) xc[(size_t)px*Dd + c] = vv;
        else       z [(size_t)px*Dd + (c-Dd)] = vv;
      }
    }
  }
}

// ---- K4: depthwise 3x3 conv SAME + bias + SiLU ----
__global__ __launch_bounds__(256) void k_conv(const float* __restrict__ xc, const float* __restrict__ cw,
                       const float* __restrict__ cb, float* __restrict__ xo){
  int idx = blockIdx.x*256 + threadIdx.x;
  if(idx >= Bn*HW*(Dd/4)) return;
  int d4 = idx % (Dd/4); int pos = (idx/(Dd/4))%HW; int b = idx/((Dd/4)*HW);
  int h = pos/Ww, w = pos%Ww;
  int d0 = d4*4;
  float4 acc = {cb[d0],cb[d0+1],cb[d0+2],cb[d0+3]};
  #pragma unroll
  for(int kh=0;kh<3;kh++){
    int hh=h+kh-1; if(hh<0||hh>=Hh) continue;
    #pragma unroll
    for(int kw=0;kw<3;kw++){
      int ww2=w+kw-1; if(ww2<0||ww2>=Ww) continue;
      float4 v = *(const float4*)(xc + ((size_t)(b*HW + hh*Ww+ww2))*Dd + d0);
      int wi = kh*3+kw;
      acc.x += v.x*cw[(d0+0)*9+wi];
      acc.y += v.y*cw[(d0+1)*9+wi];
      acc.z += v.z*cw[(d0+2)*9+wi];
      acc.w += v.w*cw[(d0+3)*9+wi];
    }
  }
  float4 o; o.x=siluf_(acc.x); o.y=siluf_(acc.y); o.z=siluf_(acc.z); o.w=siluf_(acc.w);
  *(float4*)(xo + ((size_t)(b*HW+pos))*Dd + d0) = o;
}

// ---- K5: 32-t tile, both k's of one order: x_dbl GEMM + dt + streams ----
__global__ __launch_bounds__(256) void k_xdbl(const float* __restrict__ xconv,
   const float* __restrict__ xpw, const float* __restrict__ dtw,
   const float* __restrict__ dtb, _Float16* __restrict__ dtT,
   _Float16* __restrict__ uT, float* __restrict__ BT, float* __restrict__ CT){
  __shared__ float su[Dd*36];
  __shared__ float wl[CD*193];
  __shared__ float dts[RK*36];
  int tid = threadIdx.x;
  int blk = blockIdx.x;
  int tile = blk % (Ll/32);
  int ord  = (blk/(Ll/32))&1;
  int b    = blk/((Ll/32)*2);
  int t0 = tile*32;
  // phase 0: gather tile (transposed, swizzled)
  #pragma unroll
  for(int i=0;i<6;i++){
    int f4 = tid+256*i;                 // 1536 = 32t * 48
    int r = f4/48, c4 = f4%48;
    int t = t0+r;
    int pos = ord ? ((t%Ww)*Ww + t/Ww) : t;
    float4 v = *(const float4*)(xconv + (size_t)(b*HW+pos)*Dd + 4*c4);
    int sw = 4*(c4&7);
    su[(4*c4+0)*36 + (r^sw)] = v.x;
    su[(4*c4+1)*36 + (r^sw)] = v.y;
    su[(4*c4+2)*36 + (r^sw)] = v.z;
    su[(4*c4+3)*36 + (r^sw)] = v.w;
  }
  __syncthreads();
  // phase 0.5: uT fp16 (d-major scan stream), once per (b,ord)
  if(tid < Dd){
    int d = tid;
    _Float16* up = uT + ((size_t)(b*2+ord)*Dd + d)*Ll + t0;
    #pragma unroll
    for(int r4=0;r4<8;r4++){
      float4 v = *(const float4*)(su + d*36 + 4*(r4 ^ ((d>>2)&7)));
      half4 hv; hv[0]=(_Float16)v.x; hv[1]=(_Float16)v.y; hv[2]=(_Float16)v.z; hv[3]=(_Float16)v.w;
      *(half4*)(up + 4*r4) = hv;
    }
  }
  int t4 = tid&7, cg = tid>>3;
  for(int kx=0;kx<2;kx++){
    int k = ord + 2*kx;
    bool rev = (kx==1);
    __syncthreads();
    for(int i=tid;i<CD*48;i+=256){
      int c = i/48, c4 = i%48;
      *(float4*)(wl + c*193 + 4*c4) = *(const float4*)(xpw + ((size_t)(k*CD+c))*Dd + 4*c4);
    }
    __syncthreads();
    float4 a0={0,0,0,0}, a1={0,0,0,0};
    for(int d=0; d<Dd; d++){
      float4 u4 = *(const float4*)(su + d*36 + 4*(t4 ^ ((d>>2)&7)));
      float w0 = wl[cg*193 + d];
      FMA4(a0,w0,u4);
      if(cg < CD-32){ float w1 = wl[(cg+32)*193 + d]; FMA4(a1,w1,u4); }
    }
    #pragma unroll
    for(int j=0;j<2;j++){
      if(j==1 && cg>=CD-32) break;
      int c = cg + 32*j;
      float4 a = j? a1 : a0;
      if(c < RK){
        dts[c*36 + 4*t4+0]=a.x; dts[c*36+4*t4+1]=a.y; dts[c*36+4*t4+2]=a.z; dts[c*36+4*t4+3]=a.w;
      } else {
        float* dst = (c < RK+NS) ? (BT + ((size_t)(b*Kk+k)*NS + (c-RK))*Ll)
                                 : (CT + ((size_t)(b*Kk+k)*NS + (c-RK-NS))*Ll);
        if(!rev){
          *(float4*)(dst + t0 + 4*t4) = a;
        } else {
          float4 rv; rv.x=a.w; rv.y=a.z; rv.z=a.y; rv.w=a.x;
          *(float4*)(dst + (Ll-4-t0-4*t4)) = rv;
        }
      }
    }
    __syncthreads();
    // dt phase
    int tl = tid&31, ds8 = tid>>5;
    #pragma unroll 4
    for(int i=0;i<24;i++){
      int d = ds8 + 8*i;
      float acc = dtb[k*Dd + d];
      #pragma unroll
      for(int r=0;r<RK;r++) acc = fmaf(dtw[((size_t)(k*Dd+d))*RK + r], dts[r*36 + tl], acc);
      acc = softplusf_(acc);
      int tq = rev ? (Ll-1-t0-tl) : (t0+tl);
      dtT[((size_t)(b*Kk+k)*Dd + d)*Ll + tq] = (_Float16)acc;
    }
  }
}

// ---- K6a: pass1 — per-chunk local scan: hloc + decay product ----
__global__ __launch_bounds__(256) void k_scan1(const _Float16* __restrict__ dtT,
  const _Float16* __restrict__ uT, const float* __restrict__ BT,
  const float* __restrict__ Alog, float* __restrict__ hloc, float* __restrict__ Pb){
  int blk=blockIdx.x;
  int d16 = blk % (Dd/16);
  int ch  = (blk/(Dd/16))%NCH;
  int k   = (blk/((Dd/16)*NCH))%Kk;
  int b   = blk/((Dd/16)*NCH*Kk);
  int tid=threadIdx.x;
  int g = tid>>4, n = tid&15;
  int d = d16*16 + g;
  float An = -__expf(Alog[((size_t)(k*Dd+d))*NS + n]);
  const _Float16* dp = dtT + ((size_t)(b*Kk+k)*Dd + d)*Ll + ch*CL;
  const _Float16* ub = uT  + ((size_t)(b*2+(k&1))*Dd + d)*Ll;
  const float*    Bp = BT  + ((size_t)(b*Kk+k)*NS + n)*Ll + ch*CL;
  bool rev = (k>=2);
  int s0 = ch*CL;
  float h=0.f, sdt=0.f;
  for(int tl=0; tl<CL; tl+=4){
    half4 dt4 = *(const half4*)(dp+tl);
    float4 B4 = *(const float4*)(Bp+tl);
    float u[4];
    if(!rev){
      half4 u4 = *(const half4*)(ub + s0+tl);
      u[0]=(float)u4[0]; u[1]=(float)u4[1]; u[2]=(float)u4[2]; u[3]=(float)u4[3];
    } else {
      half4 u4 = *(const half4*)(ub + (Ll-4-s0-tl));
      u[0]=(float)u4[3]; u[1]=(float)u4[2]; u[2]=(float)u4[1]; u[3]=(float)u4[0];
    }
    float Ba[4] = {B4.x,B4.y,B4.z,B4.w};
    #pragma unroll
    for(int j=0;j<4;j++){
      float dtv = (float)dt4[j];
      sdt += dtv;
      float ae = __expf(dtv*An);
      h = h*ae + dtv*u[j]*Ba[j];
    }
  }
  size_t o = (((size_t)(b*Kk+k)*NCH + ch)*Dd + d)*NS + n;
  hloc[o] = h;
  Pb[o]   = __expf(An*sdt);
}

// ---- K6b: combine ----
__global__ __launch_bounds__(256) void k_comb(const float* __restrict__ hloc,
  const float* __restrict__ Pb, float* __restrict__ Hin){
  int idx = blockIdx.x*256 + threadIdx.x;
  int inner = idx % (Dd*NS);
  int bk = idx / (Dd*NS);
  size_t base = (size_t)bk*NCH*Dd*NS + inner;
  float H = 0.f;
  for(int ch=0; ch<NCH; ch++){
    size_t o = base + (size_t)ch*Dd*NS;
    Hin[o] = H;
    H = Pb[o]*H + hloc[o];
  }
}

// ---- K6c: pass2 ----
__global__ __launch_bounds__(256) void k_scan2(const _Float16* __restrict__ dtT,
  const _Float16* __restrict__ uT, const float* __restrict__ BT,
  const float* __restrict__ CT, const float* __restrict__ Alog,
  const float* __restrict__ Ds, const float* __restrict__ Hin,
  float* __restrict__ yB){
  int blk=blockIdx.x;
  int d16 = blk % (Dd/16);
  int ch  = (blk/(Dd/16))%NCH;
  int k   = (blk/((Dd/16)*NCH))%Kk;
  int b   = blk/((Dd/16)*NCH*Kk);
  int tid=threadIdx.x;
  int g = tid>>4, n = tid&15;
  int d = d16*16 + g;
  float An = -__expf(Alog[((size_t)(k*Dd+d))*NS + n]);
  float Dv = Ds[k*Dd+d];
  const _Float16* dp = dtT + ((size_t)(b*Kk+k)*Dd + d)*Ll + ch*CL;
  const _Float16* ub = uT  + ((size_t)(b*2+(k&1))*Dd + d)*Ll;
  const float*    Bp = BT  + ((size_t)(b*Kk+k)*NS + n)*Ll + ch*CL;
  const float*    Cp = CT  + ((size_t)(b*Kk+k)*NS + n)*Ll + ch*CL;
  float*          yp = yB  + ((size_t)(b*Kk+k)*Ll)*Dd + d;
  bool rev = (k>=2);
  int s0 = ch*CL;
  float h = Hin[(((size_t)(b*Kk+k)*NCH + ch)*Dd + d)*NS + n];
  for(int tl=0; tl<CL; tl+=4){
    half4 dt4 = *(const half4*)(dp+tl);
    float4 B4 = *(const float4*)(Bp+tl);
    float4 C4 = *(const float4*)(Cp+tl);
    float u[4];
    if(!rev){
      half4 u4 = *(const half4*)(ub + s0+tl);
      u[0]=(float)u4[0]; u[1]=(float)u4[1]; u[2]=(float)u4[2]; u[3]=(float)u4[3];
    } else {
      half4 u4 = *(const half4*)(ub + (Ll-4-s0-tl));
      u[0]=(float)u4[3]; u[1]=(float)u4[2]; u[2]=(float)u4[1]; u[3]=(float)u4[0];
    }
    float Ba[4] = {B4.x,B4.y,B4.z,B4.w};
    float Ca[4] = {C4.x,C4.y,C4.z,C4.w};
    float yv[4];
    #pragma unroll
    for(int j=0;j<4;j++){
      float dtv = (float)dt4[j];
      float ae = __expf(dtv*An);
      h = h*ae + dtv*u[j]*Ba[j];
      float p = h*Ca[j];
      p += __shfl_xor(p,1); p += __shfl_xor(p,2); p += __shfl_xor(p,4); p += __shfl_xor(p,8);
      yv[j] = p + Dv*u[j];
    }
    if(n==0){
      yp[(size_t)(s0+tl+0)*Dd] = yv[0];
      yp[(size_t)(s0+tl+1)*Dd] = yv[1];
      yp[(size_t)(s0+tl+2)*Dd] = yv[2];
      yp[(size_t)(s0+tl+3)*Dd] = yv[3];
    }
  }
}

// ---- K7: 32-px tile: merge 4 dirs + LN(192) + gate + out_proj GEMM + residual ----
__global__ __launch_bounds__(256) void k_merge(const float* __restrict__ yB,
  const float* __restrict__ og, const float* __restrict__ ob,
  const float* __restrict__ zB, const float* __restrict__ opw,
  const float* __restrict__ xi, float* __restrict__ ot){
  __shared__ float yv[Dd*36];
  __shared__ float wl[48*193];
  int tid = threadIdx.x;
  int pix0 = blockIdx.x*32;
  int b = pix0/HW;
  int pos0 = pix0%HW;
  size_t ybase = (size_t)b*Kk*Ll*Dd;
  #pragma unroll
  for(int i=0;i<6;i++){
    int f4 = tid+256*i;                 // 1536 = 32px*48
    int r = f4/48, c4 = f4%48;
    int pos = pos0+r;
    int lwh = (pos%Ww)*Ww + pos/Ww;
    float4 v0 = *(const float4*)(yB + ybase + ((size_t)(0*Ll) + pos)*Dd + 4*c4);
    float4 v2 = *(const float4*)(yB + ybase + ((size_t)(2*Ll) + (Ll-1-pos))*Dd + 4*c4);
    float4 v1 = *(const float4*)(yB + ybase + ((size_t)(1*Ll) + lwh)*Dd + 4*c4);
    float4 v3 = *(const float4*)(yB + ybase + ((size_t)(3*Ll) + (Ll-1-lwh))*Dd + 4*c4);
    float4 v; v.x=v0.x+v1.x+v2.x+v3.x; v.y=v0.y+v1.y+v2.y+v3.y;
    v.z=v0.z+v1.z+v2.z+v3.z; v.w=v0.w+v1.w+v2.w+v3.w;
    int sw = 4*(c4&7);
    yv[(4*c4+0)*36 + (r^sw)] = v.x;
    yv[(4*c4+1)*36 + (r^sw)] = v.y;
    yv[(4*c4+2)*36 + (r^sw)] = v.z;
    yv[(4*c4+3)*36 + (r^sw)] = v.w;
  }
  __syncthreads();
  // LN(192) + silu(z) gate
  {
    int px = tid>>3, gg = tid&7;
    float sm=0.f, sq=0.f;
    float vals[24];
    #pragma unroll
    for(int i=0;i<24;i++){
      int d = gg + 8*i;
      float v = yv[d*36 + (px ^ (4*((d>>2)&7)))];
      vals[i]=v; sm+=v; sq+=v*v;
    }
    sm += __shfl_xor(sm,1); sq += __shfl_xor(sq,1);
    sm += __shfl_xor(sm,2); sq += __shfl_xor(sq,2);
    sm += __shfl_xor(sm,4); sq += __shfl_xor(sq,4);
    float mean = sm*(1.0f/Dd);
    float var  = sq*(1.0f/Dd) - mean*mean;
    float rs = rsqrtf(var + 1e-5f);
    #pragma unroll
    for(int i=0;i<24;i++){
      int d = gg + 8*i;
      float zv = zB[(size_t)(pix0+px)*Dd + d];
      yv[d*36 + (px ^ (4*((d>>2)&7)))] = ((vals[i]-mean)*rs*og[d] + ob[d]) * siluf_(zv);
    }
  }
  __syncthreads();
  int t4 = tid&7, cg = tid>>3;
  for(int p=0;p<2;p++){
    if(p) __syncthreads();
    for(int i=tid;i<48*48;i+=256){
      int c=i/48, c4=i%48;
      *(float4*)(wl + c*193 + 4*c4) = *(const float4*)(opw + (size_t)(48*p+c)*Dd + 4*c4);
    }
    __syncthreads();
    float4 a0={0,0,0,0}, a1={0,0,0,0};
    for(int d=0;d<Dd;d++){
      float4 u4 = *(const float4*)(yv + d*36 + 4*(t4 ^ ((d>>2)&7)));
      float w0 = wl[cg*193+d];
      FMA4(a0,w0,u4);
      if(cg<16){ float w1 = wl[(cg+32)*193+d]; FMA4(a1,w1,u4); }
    }
    #pragma unroll
    for(int j=0;j<2;j++){
      if(j==1 && cg>=16) break;
      int c = 48*p + cg + 32*j;
      float4 a = j?a1:a0;
      #pragma unroll
      for(int q=0;q<4;q++){
        int px = pix0 + 4*t4 + q;
        float vv = (q==0)?a.x:(q==1)?a.y:(q==2)?a.z:a.w;
        ot[(size_t)px*Cc + c] = vv + xi[(size_t)px*Cc + c];
      }
    }
  }
}

// ---- K8: (B,HW,C) -> (B,C,HW) tiled transpose ----
__global__ __launch_bounds__(256) void k_outT(const float* __restrict__ ot, float* __restrict__ out){
  __shared__ float tile[64][33];
  int p0=blockIdx.x*64, c0=blockIdx.y*32, b=blockIdx.z;
  int cl=threadIdx.x%32, pl=threadIdx.x/32;
  for(int i=0;i<8;i++){
    int p = pl+i*8;
    tile[p][cl] = ot[((size_t)(b*HW+p0+p))*Cc + c0+cl];
  }
  __syncthreads();
  int pj=threadIdx.x%64, ci=threadIdx.x/64;
  for(int i=0;i<8;i++){
    int c=ci+i*4;
    out[((size_t)(b*Cc+c0+c))*HW + p0+pj] = tile[pj][c];
  }
}

extern "C" void kernel_launch(void* const* d_in, const int* in_sizes, int n_in,
                              void* d_out, int out_size, void* d_ws, size_t ws_size,
                              hipStream_t stream){
  const float* x   = (const float*)d_in[0];
  const float* cw1 = (const float*)d_in[1];
  const float* cw2 = (const float*)d_in[2];
  const float* lng = (const float*)d_in[3];
  const float* lnb = (const float*)d_in[4];
  const float* ipw = (const float*)d_in[5];
  const float* cvw = (const float*)d_in[6];
  const float* cvb = (const float*)d_in[7];
  const float* xpw = (const float*)d_in[8];
  const float* dtw = (const float*)d_in[9];
  const float* dtb = (const float*)d_in[10];
  const float* alg = (const float*)d_in[11];
  const float* ds  = (const float*)d_in[12];
  const float* ong = (const float*)d_in[13];
  const float* onb = (const float*)d_in[14];
  const float* opw = (const float*)d_in[15];
  float* out = (float*)d_out;
  float* ws = (float*)d_ws;

  float* s_   = ws;                          // 384
  float* a_   = s_  + 384;                   // 384
  float* xi_  = a_  + 384;                   // 884736
  float* xc_  = xi_ + 884736;                // 1769472 (reused: hloc+P after conv)
  float* z_   = xc_ + 1769472;               // 1769472
  float* xo_  = z_  + 1769472;               // 1769472
  _Float16* dtT_ = (_Float16*)(xo_ + 1769472);   // 7077888 halves
  _Float16* uT_  = dtT_ + 7077888;               // 3538944 halves
  float* BT_  = (float*)(uT_ + 3538944);     // 589824
  float* CT_  = BT_ + 589824;                // 589824
  float* yB_  = CT_ + 589824;                // 7077888
  float* ot_  = yB_ + 7077888;               // 884736 (reused: Hinit before merge)

  float* hloc_ = xc_;                        // 786432
  float* Pb_   = xc_ + 786432;               // 786432
  float* Hin_  = ot_;                        // 786432

  k_mean  <<<Bn*Cc, 256, 0, stream>>>(x, s_);
  k_ca    <<<1, 384, 0, stream>>>(s_, cw1, cw2, a_);
  k_xca   <<<dim3(HW/64, Cc/32, Bn), 256, 0, stream>>>(x, a_, xi_);
  k_lnproj<<<Bn*HW/32, 256, 0, stream>>>(xi_, lng, lnb, ipw, xc_, z_);
  k_conv  <<<(Bn*HW*(Dd/4))/256, 256, 0, stream>>>(xc_, cvw, cvb, xo_);
  k_xdbl  <<<Bn*2*(Ll/32), 256, 0, stream>>>(xo_, xpw, dtw, dtb, dtT_, uT_, BT_, CT_);
  k_scan1 <<<Bn*Kk*NCH*(Dd/16), 256, 0, stream>>>(dtT_, uT_, BT_, alg, hloc_, Pb_);
  k_comb  <<<(Bn*Kk*Dd*NS)/256, 256, 0, stream>>>(hloc_, Pb_, Hin_);
  k_scan2 <<<Bn*Kk*NCH*(Dd/16), 256, 0, stream>>>(dtT_, uT_, BT_, CT_, alg, ds, Hin_, yB_);
  k_merge <<<Bn*HW/32, 256, 0, stream>>>(yB_, ong, onb, z_, opw, xi_, ot_);
  k_outT  <<<dim3(HW/64, Cc/32, Bn), 256, 0, stream>>>(ot_, out);
}

// Round 4
// 316.325 us; speedup vs baseline: 4.5864x; 1.3798x over previous
//
#include <hip/hip_runtime.h>
#include <math.h>

#define Bn 4
#define Cc 96
#define Hh 48
#define Ww 48
#define HW 2304
#define Dd 192
#define NS 16
#define Kk 4
#define RK 6
#define CD 38   // RK + 2*NS
#define Ll 2304
#define NCH 16
#define CL 144  // Ll / NCH

typedef _Float16 half4 __attribute__((ext_vector_type(4)));
typedef float f4v __attribute__((ext_vector_type(4)));

#define FMA4(A,W,U) { A.x=fmaf(W,U.x,A.x); A.y=fmaf(W,U.y,A.y); A.z=fmaf(W,U.z,A.z); A.w=fmaf(W,U.w,A.w); }

__device__ __forceinline__ float sigmoidf_(float x){ return 1.0f/(1.0f+__expf(-x)); }
__device__ __forceinline__ float siluf_(float x){ return x*sigmoidf_(x); }
__device__ __forceinline__ float softplusf_(float x){ return (x>20.0f)? x : log1pf(__expf(x)); }

// ---- K1a: s[b,c] = mean over HW ----
__global__ __launch_bounds__(256) void k_mean(const float* __restrict__ x, float* __restrict__ s){
  int bc = blockIdx.x;
  const float* p = x + (size_t)bc*HW;
  float acc = 0.f;
  for(int i=threadIdx.x;i<HW;i+=256) acc += p[i];
  __shared__ float red[256];
  red[threadIdx.x]=acc; __syncthreads();
  for(int o=128;o>0;o>>=1){ if(threadIdx.x<o) red[threadIdx.x]+=red[threadIdx.x+o]; __syncthreads(); }
  if(threadIdx.x==0) s[bc]=red[0]*(1.0f/HW);
}

// ---- K1b: a = sigmoid(relu(s@w1^T)@w2^T) ----
__global__ __launch_bounds__(384) void k_ca(const float* __restrict__ s, const float* __restrict__ w1,
                     const float* __restrict__ w2, float* __restrict__ a){
  __shared__ float hid[Bn*RK];
  int tid=threadIdx.x;
  if(tid<Bn*RK){
    int b=tid/RK, r=tid%RK;
    float acc=0.f;
    for(int c=0;c<Cc;c++) acc += s[b*Cc+c]*w1[r*Cc+c];
    hid[tid]=fmaxf(acc,0.f);
  }
  __syncthreads();
  int b=tid/Cc, c=tid%Cc;
  float acc=0.f;
  for(int r=0;r<RK;r++) acc += hid[b*RK+r]*w2[c*RK+r];
  a[tid]=sigmoidf_(acc);
}

// ---- K2: xi[b,pos,c] = x[b,c,pos]*a[b,c]  (tiled transpose) ----
__global__ __launch_bounds__(256) void k_xca(const float* __restrict__ x, const float* __restrict__ a,
                      float* __restrict__ xi){
  __shared__ float tile[32][65];
  int p0 = blockIdx.x*64, c0 = blockIdx.y*32, b = blockIdx.z;
  int pj = threadIdx.x%64, ci = threadIdx.x/64;
  for(int i=0;i<8;i++){
    int c = c0+ci+i*4;
    tile[ci+i*4][pj] = x[((size_t)(b*Cc+c))*HW + p0+pj]*a[b*Cc+c];
  }
  __syncthreads();
  int cl = threadIdx.x%32, pl = threadIdx.x/32;
  for(int i=0;i<8;i++){
    int p = pl + i*8;
    xi[((size_t)(b*HW + p0+p))*Cc + c0+cl] = tile[cl][p];
  }
}

// ---- K3: 32-px tile: LN(96) + in_proj GEMM -> xc, z ----
__global__ __launch_bounds__(256) void k_lnproj(const float* __restrict__ xi,
    const float* __restrict__ g, const float* __restrict__ bta,
    const float* __restrict__ w, float* __restrict__ xc, float* __restrict__ z){
  __shared__ float su[Cc*36];     // t-minor swizzled
  __shared__ float wl[128*97];
  int tid = threadIdx.x;
  int pix0 = blockIdx.x*32;
  #pragma unroll
  for(int i=0;i<3;i++){
    int f4 = tid + 256*i;               // 768 = 32px * 24
    int px = f4/24, c4 = f4%24;
    float4 v = *(const float4*)(xi + (size_t)(pix0+px)*Cc + 4*c4);
    int sw = 4*(c4&7);
    su[(4*c4+0)*36 + (px^sw)] = v.x;
    su[(4*c4+1)*36 + (px^sw)] = v.y;
    su[(4*c4+2)*36 + (px^sw)] = v.z;
    su[(4*c4+3)*36 + (px^sw)] = v.w;
  }
  __syncthreads();
  {
    int px = tid>>3, gg = tid&7;
    float sm=0.f, sq=0.f;
    float vals[12];
    #pragma unroll
    for(int i=0;i<12;i++){
      int d = gg + 8*i;
      float v = su[d*36 + (px ^ (4*((d>>2)&7)))];
      vals[i]=v; sm+=v; sq+=v*v;
    }
    sm += __shfl_xor(sm,1); sq += __shfl_xor(sq,1);
    sm += __shfl_xor(sm,2); sq += __shfl_xor(sq,2);
    sm += __shfl_xor(sm,4); sq += __shfl_xor(sq,4);
    float mean = sm*(1.0f/Cc);
    float var  = sq*(1.0f/Cc) - mean*mean;
    float rs = rsqrtf(var + 1e-5f);
    #pragma unroll
    for(int i=0;i<12;i++){
      int d = gg + 8*i;
      su[d*36 + (px ^ (4*((d>>2)&7)))] = (vals[i]-mean)*rs*g[d] + bta[d];
    }
  }
  __syncthreads();
  int t4 = tid&7, cg = tid>>3;
  for(int p=0;p<3;p++){
    if(p) __syncthreads();
    #pragma unroll
    for(int i=0;i<12;i++){
      int f4 = tid + 256*i;             // 3072 = 128*24
      int r = f4/24, c4 = f4%24;
      *(float4*)(wl + r*97 + 4*c4) = *(const float4*)(w + (size_t)(128*p + r)*Cc + 4*c4);
    }
    __syncthreads();
    float4 a0={0,0,0,0},a1={0,0,0,0},a2={0,0,0,0},a3={0,0,0,0};
    for(int d=0; d<Cc; d++){
      float4 u4 = *(const float4*)(su + d*36 + 4*(t4 ^ ((d>>2)&7)));
      float w0 = wl[(cg+  0)*97 + d];
      float w1 = wl[(cg+ 32)*97 + d];
      float w2 = wl[(cg+ 64)*97 + d];
      float w3 = wl[(cg+ 96)*97 + d];
      FMA4(a0,w0,u4); FMA4(a1,w1,u4); FMA4(a2,w2,u4); FMA4(a3,w3,u4);
    }
    #pragma unroll
    for(int j=0;j<4;j++){
      int c = 128*p + cg + 32*j;
      float4 a = (j==0)?a0:(j==1)?a1:(j==2)?a2:a3;
      #pragma unroll
      for(int q=0;q<4;q++){
        int px = pix0 + 4*t4 + q;
        float vv = (q==0)?a.x:(q==1)?a.y:(q==2)?a.z:a.w;
        if(c < Dd) xc[(size_t)px*Dd + c] = vv;
        else       z [(size_t)px*Dd + (c-Dd)] = vv;
      }
    }
  }
}

// ---- K4: depthwise 3x3 conv SAME + bias + SiLU ----
__global__ __launch_bounds__(256) void k_conv(const float* __restrict__ xc, const float* __restrict__ cw,
                       const float* __restrict__ cb, float* __restrict__ xo){
  int idx = blockIdx.x*256 + threadIdx.x;
  if(idx >= Bn*HW*(Dd/4)) return;
  int d4 = idx % (Dd/4); int pos = (idx/(Dd/4))%HW; int b = idx/((Dd/4)*HW);
  int h = pos/Ww, w = pos%Ww;
  int d0 = d4*4;
  float4 acc = {cb[d0],cb[d0+1],cb[d0+2],cb[d0+3]};
  #pragma unroll
  for(int kh=0;kh<3;kh++){
    int hh=h+kh-1; if(hh<0||hh>=Hh) continue;
    #pragma unroll
    for(int kw=0;kw<3;kw++){
      int ww2=w+kw-1; if(ww2<0||ww2>=Ww) continue;
      float4 v = *(const float4*)(xc + ((size_t)(b*HW + hh*Ww+ww2))*Dd + d0);
      int wi = kh*3+kw;
      acc.x += v.x*cw[(d0+0)*9+wi];
      acc.y += v.y*cw[(d0+1)*9+wi];
      acc.z += v.z*cw[(d0+2)*9+wi];
      acc.w += v.w*cw[(d0+3)*9+wi];
    }
  }
  float4 o; o.x=siluf_(acc.x); o.y=siluf_(acc.y); o.z=siluf_(acc.z); o.w=siluf_(acc.w);
  *(float4*)(xo + ((size_t)(b*HW+pos))*Dd + d0) = o;
}

// ---- K5: 32-t tile, both k's of one order: x_dbl GEMM + dt + streams ----
// B/C now fused t-major: BC[b,k][t][32] (n<16 = B, n>=16 = C)
__global__ __launch_bounds__(256) void k_xdbl(const float* __restrict__ xconv,
   const float* __restrict__ xpw, const float* __restrict__ dtw,
   const float* __restrict__ dtb, _Float16* __restrict__ dtT,
   _Float16* __restrict__ uT, float* __restrict__ BC){
  __shared__ float su[Dd*36];
  __shared__ float wl[CD*193];
  __shared__ float dts[RK*36];
  int tid = threadIdx.x;
  int blk = blockIdx.x;
  int tile = blk % (Ll/32);
  int ord  = (blk/(Ll/32))&1;
  int b    = blk/((Ll/32)*2);
  int t0 = tile*32;
  #pragma unroll
  for(int i=0;i<6;i++){
    int f4 = tid+256*i;                 // 1536 = 32t * 48
    int r = f4/48, c4 = f4%48;
    int t = t0+r;
    int pos = ord ? ((t%Ww)*Ww + t/Ww) : t;
    float4 v = *(const float4*)(xconv + (size_t)(b*HW+pos)*Dd + 4*c4);
    int sw = 4*(c4&7);
    su[(4*c4+0)*36 + (r^sw)] = v.x;
    su[(4*c4+1)*36 + (r^sw)] = v.y;
    su[(4*c4+2)*36 + (r^sw)] = v.z;
    su[(4*c4+3)*36 + (r^sw)] = v.w;
  }
  __syncthreads();
  if(tid < Dd){
    int d = tid;
    _Float16* up = uT + ((size_t)(b*2+ord)*Dd + d)*Ll + t0;
    #pragma unroll
    for(int r4=0;r4<8;r4++){
      float4 v = *(const float4*)(su + d*36 + 4*(r4 ^ ((d>>2)&7)));
      half4 hv; hv[0]=(_Float16)v.x; hv[1]=(_Float16)v.y; hv[2]=(_Float16)v.z; hv[3]=(_Float16)v.w;
      *(half4*)(up + 4*r4) = hv;
    }
  }
  int t4 = tid&7, cg = tid>>3;
  for(int kx=0;kx<2;kx++){
    int k = ord + 2*kx;
    bool rev = (kx==1);
    __syncthreads();
    for(int i=tid;i<CD*48;i+=256){
      int c = i/48, c4 = i%48;
      *(float4*)(wl + c*193 + 4*c4) = *(const float4*)(xpw + ((size_t)(k*CD+c))*Dd + 4*c4);
    }
    __syncthreads();
    float4 a0={0,0,0,0}, a1={0,0,0,0};
    for(int d=0; d<Dd; d++){
      float4 u4 = *(const float4*)(su + d*36 + 4*(t4 ^ ((d>>2)&7)));
      float w0 = wl[cg*193 + d];
      FMA4(a0,w0,u4);
      if(cg < CD-32){ float w1 = wl[(cg+32)*193 + d]; FMA4(a1,w1,u4); }
    }
    #pragma unroll
    for(int j=0;j<2;j++){
      if(j==1 && cg>=CD-32) break;
      int c = cg + 32*j;
      float4 a = j? a1 : a0;
      if(c < RK){
        dts[c*36 + 4*t4+0]=a.x; dts[c*36+4*t4+1]=a.y; dts[c*36+4*t4+2]=a.z; dts[c*36+4*t4+3]=a.w;
      } else {
        int nn = c - RK;   // 0..31
        float* dst = BC + ((size_t)(b*Kk+k)*Ll)*32 + nn;
        float av[4] = {a.x,a.y,a.z,a.w};
        #pragma unroll
        for(int q=0;q<4;q++){
          int t = t0 + 4*t4 + q;
          int tq = rev ? (Ll-1-t) : t;
          dst[(size_t)tq*32] = av[q];
        }
      }
    }
    __syncthreads();
    int tl = tid&31, ds8 = tid>>5;
    #pragma unroll 4
    for(int i=0;i<24;i++){
      int d = ds8 + 8*i;
      float acc = dtb[k*Dd + d];
      #pragma unroll
      for(int r=0;r<RK;r++) acc = fmaf(dtw[((size_t)(k*Dd+d))*RK + r], dts[r*36 + tl], acc);
      acc = softplusf_(acc);
      int tq = rev ? (Ll-1-t0-tl) : (t0+tl);
      dtT[((size_t)(b*Kk+k)*Dd + d)*Ll + tq] = (_Float16)acc;
    }
  }
}

// ---- K6a: pass1 — 4 states per lane, no cross-lane ops ----
__global__ __launch_bounds__(256) void k_scan1(const _Float16* __restrict__ dtT,
  const _Float16* __restrict__ uT, const float* __restrict__ BC,
  const float* __restrict__ Alog, float* __restrict__ hloc, float* __restrict__ Pb){
  int blk=blockIdx.x;
  int dblk = blk % 3;
  int ch  = (blk/3)%NCH;
  int k   = (blk/(3*NCH))%Kk;
  int b   = blk/(3*NCH*Kk);
  int tid=threadIdx.x;
  int nq = tid&3, dl = tid>>2;
  int d = dblk*64 + dl;
  f4v An;
  #pragma unroll
  for(int i=0;i<4;i++) An[i] = -__expf(Alog[((size_t)(k*Dd+d))*NS + 4*nq + i]);
  const _Float16* dp = dtT + ((size_t)(b*Kk+k)*Dd + d)*Ll + ch*CL;
  const _Float16* ub = uT  + ((size_t)(b*2+(k&1))*Dd + d)*Ll;
  const float*    bc = BC  + ((size_t)(b*Kk+k)*Ll + ch*CL)*32 + 4*nq;
  bool rev = (k>=2);
  int s0 = ch*CL;
  f4v h = {0,0,0,0};
  float sdt = 0.f;
  for(int tl=0; tl<CL; tl+=4){
    half4 dt4 = *(const half4*)(dp+tl);
    float u[4];
    if(!rev){
      half4 u4 = *(const half4*)(ub + s0+tl);
      u[0]=(float)u4[0]; u[1]=(float)u4[1]; u[2]=(float)u4[2]; u[3]=(float)u4[3];
    } else {
      half4 u4 = *(const half4*)(ub + (Ll-4-s0-tl));
      u[0]=(float)u4[3]; u[1]=(float)u4[2]; u[2]=(float)u4[1]; u[3]=(float)u4[0];
    }
    #pragma unroll
    for(int j=0;j<4;j++){
      f4v Bv = *(const f4v*)(bc + (size_t)(tl+j)*32);
      float dtv = (float)dt4[j];
      sdt += dtv;
      float xB = dtv*u[j];
      #pragma unroll
      for(int i=0;i<4;i++){
        float ae = __expf(dtv*An[i]);
        h[i] = fmaf(h[i], ae, xB*Bv[i]);
      }
    }
  }
  size_t o = (((size_t)(b*Kk+k)*NCH + ch)*Dd + d)*NS + 4*nq;
  *(f4v*)(hloc + o) = h;
  f4v P;
  #pragma unroll
  for(int i=0;i<4;i++) P[i] = __expf(An[i]*sdt);
  *(f4v*)(Pb + o) = P;
}

// ---- K6b: combine ----
__global__ __launch_bounds__(256) void k_comb(const float* __restrict__ hloc,
  const float* __restrict__ Pb, float* __restrict__ Hin){
  int idx = blockIdx.x*256 + threadIdx.x;
  int inner = idx % (Dd*NS);
  int bk = idx / (Dd*NS);
  size_t base = (size_t)bk*NCH*Dd*NS + inner;
  float H = 0.f;
  for(int ch=0; ch<NCH; ch++){
    size_t o = base + (size_t)ch*Dd*NS;
    Hin[o] = H;
    H = Pb[o]*H + hloc[o];
  }
}

// ---- K6c: pass2 — 4 states per lane, depth-2 shuffle off critical path ----
__global__ __launch_bounds__(256) void k_scan2(const _Float16* __restrict__ dtT,
  const _Float16* __restrict__ uT, const float* __restrict__ BC,
  const float* __restrict__ Alog, const float* __restrict__ Ds,
  const float* __restrict__ Hin, float* __restrict__ yB){
  int blk=blockIdx.x;
  int dblk = blk % 3;
  int ch  = (blk/3)%NCH;
  int k   = (blk/(3*NCH))%Kk;
  int b   = blk/(3*NCH*Kk);
  int tid=threadIdx.x;
  int nq = tid&3, dl = tid>>2;
  int d = dblk*64 + dl;
  f4v An;
  #pragma unroll
  for(int i=0;i<4;i++) An[i] = -__expf(Alog[((size_t)(k*Dd+d))*NS + 4*nq + i]);
  float Dv = Ds[k*Dd+d];
  const _Float16* dp = dtT + ((size_t)(b*Kk+k)*Dd + d)*Ll + ch*CL;
  const _Float16* ub = uT  + ((size_t)(b*2+(k&1))*Dd + d)*Ll;
  const float*    bc = BC  + ((size_t)(b*Kk+k)*Ll + ch*CL)*32 + 4*nq;
  float*          yp = yB  + ((size_t)(b*Kk+k)*Ll)*Dd + d;
  bool rev = (k>=2);
  int s0 = ch*CL;
  f4v h = *(const f4v*)(Hin + (((size_t)(b*Kk+k)*NCH + ch)*Dd + d)*NS + 4*nq);
  for(int tl=0; tl<CL; tl+=4){
    half4 dt4 = *(const half4*)(dp+tl);
    float u[4];
    if(!rev){
      half4 u4 = *(const half4*)(ub + s0+tl);
      u[0]=(float)u4[0]; u[1]=(float)u4[1]; u[2]=(float)u4[2]; u[3]=(float)u4[3];
    } else {
      half4 u4 = *(const half4*)(ub + (Ll-4-s0-tl));
      u[0]=(float)u4[3]; u[1]=(float)u4[2]; u[2]=(float)u4[1]; u[3]=(float)u4[0];
    }
    #pragma unroll
    for(int j=0;j<4;j++){
      f4v Bv = *(const f4v*)(bc + (size_t)(tl+j)*32);
      f4v Cv = *(const f4v*)(bc + (size_t)(tl+j)*32 + 16);
      float dtv = (float)dt4[j];
      float xB = dtv*u[j];
      #pragma unroll
      for(int i=0;i<4;i++){
        float ae = __expf(dtv*An[i]);
        h[i] = fmaf(h[i], ae, xB*Bv[i]);
      }
      float p = h[0]*Cv[0];
      p = fmaf(h[1],Cv[1],p); p = fmaf(h[2],Cv[2],p); p = fmaf(h[3],Cv[3],p);
      p += __shfl_xor(p,1); p += __shfl_xor(p,2);
      if(nq==0) yp[(size_t)(s0+tl+j)*Dd] = p + Dv*u[j];
    }
  }
}

// ---- K7: 32-px tile: merge 4 dirs + LN(192) + gate + out_proj GEMM + residual ----
__global__ __launch_bounds__(256) void k_merge(const float* __restrict__ yB,
  const float* __restrict__ og, const float* __restrict__ ob,
  const float* __restrict__ zB, const float* __restrict__ opw,
  const float* __restrict__ xi, float* __restrict__ ot){
  __shared__ float yv[Dd*36];
  __shared__ float wl[48*193];
  int tid = threadIdx.x;
  int pix0 = blockIdx.x*32;
  int b = pix0/HW;
  int pos0 = pix0%HW;
  size_t ybase = (size_t)b*Kk*Ll*Dd;
  #pragma unroll
  for(int i=0;i<6;i++){
    int f4 = tid+256*i;                 // 1536 = 32px*48
    int r = f4/48, c4 = f4%48;
    int pos = pos0+r;
    int lwh = (pos%Ww)*Ww + pos/Ww;
    float4 v0 = *(const float4*)(yB + ybase + ((size_t)(0*Ll) + pos)*Dd + 4*c4);
    float4 v2 = *(const float4*)(yB + ybase + ((size_t)(2*Ll) + (Ll-1-pos))*Dd + 4*c4);
    float4 v1 = *(const float4*)(yB + ybase + ((size_t)(1*Ll) + lwh)*Dd + 4*c4);
    float4 v3 = *(const float4*)(yB + ybase + ((size_t)(3*Ll) + (Ll-1-lwh))*Dd + 4*c4);
    float4 v; v.x=v0.x+v1.x+v2.x+v3.x; v.y=v0.y+v1.y+v2.y+v3.y;
    v.z=v0.z+v1.z+v2.z+v3.z; v.w=v0.w+v1.w+v2.w+v3.w;
    int sw = 4*(c4&7);
    yv[(4*c4+0)*36 + (r^sw)] = v.x;
    yv[(4*c4+1)*36 + (r^sw)] = v.y;
    yv[(4*c4+2)*36 + (r^sw)] = v.z;
    yv[(4*c4+3)*36 + (r^sw)] = v.w;
  }
  __syncthreads();
  {
    int px = tid>>3, gg = tid&7;
    float sm=0.f, sq=0.f;
    float vals[24];
    #pragma unroll
    for(int i=0;i<24;i++){
      int d = gg + 8*i;
      float v = yv[d*36 + (px ^ (4*((d>>2)&7)))];
      vals[i]=v; sm+=v; sq+=v*v;
    }
    sm += __shfl_xor(sm,1); sq += __shfl_xor(sq,1);
    sm += __shfl_xor(sm,2); sq += __shfl_xor(sq,2);
    sm += __shfl_xor(sm,4); sq += __shfl_xor(sq,4);
    float mean = sm*(1.0f/Dd);
    float var  = sq*(1.0f/Dd) - mean*mean;
    float rs = rsqrtf(var + 1e-5f);
    #pragma unroll
    for(int i=0;i<24;i++){
      int d = gg + 8*i;
      float zv = zB[(size_t)(pix0+px)*Dd + d];
      yv[d*36 + (px ^ (4*((d>>2)&7)))] = ((vals[i]-mean)*rs*og[d] + ob[d]) * siluf_(zv);
    }
  }
  __syncthreads();
  int t4 = tid&7, cg = tid>>3;
  for(int p=0;p<2;p++){
    if(p) __syncthreads();
    for(int i=tid;i<48*48;i+=256){
      int c=i/48, c4=i%48;
      *(float4*)(wl + c*193 + 4*c4) = *(const float4*)(opw + (size_t)(48*p+c)*Dd + 4*c4);
    }
    __syncthreads();
    float4 a0={0,0,0,0}, a1={0,0,0,0};
    for(int d=0;d<Dd;d++){
      float4 u4 = *(const float4*)(yv + d*36 + 4*(t4 ^ ((d>>2)&7)));
      float w0 = wl[cg*193+d];
      FMA4(a0,w0,u4);
      if(cg<16){ float w1 = wl[(cg+32)*193+d]; FMA4(a1,w1,u4); }
    }
    #pragma unroll
    for(int j=0;j<2;j++){
      if(j==1 && cg>=16) break;
      int c = 48*p + cg + 32*j;
      float4 a = j?a1:a0;
      #pragma unroll
      for(int q=0;q<4;q++){
        int px = pix0 + 4*t4 + q;
        float vv = (q==0)?a.x:(q==1)?a.y:(q==2)?a.z:a.w;
        ot[(size_t)px*Cc + c] = vv + xi[(size_t)px*Cc + c];
      }
    }
  }
}

// ---- K8: (B,HW,C) -> (B,C,HW) tiled transpose ----
__global__ __launch_bounds__(256) void k_outT(const float* __restrict__ ot, float* __restrict__ out){
  __shared__ float tile[64][33];
  int p0=blockIdx.x*64, c0=blockIdx.y*32, b=blockIdx.z;
  int cl=threadIdx.x%32, pl=threadIdx.x/32;
  for(int i=0;i<8;i++){
    int p = pl+i*8;
    tile[p][cl] = ot[((size_t)(b*HW+p0+p))*Cc + c0+cl];
  }
  __syncthreads();
  int pj=threadIdx.x%64, ci=threadIdx.x/64;
  for(int i=0;i<8;i++){
    int c=ci+i*4;
    out[((size_t)(b*Cc+c0+c))*HW + p0+pj] = tile[pj][c];
  }
}

extern "C" void kernel_launch(void* const* d_in, const int* in_sizes, int n_in,
                              void* d_out, int out_size, void* d_ws, size_t ws_size,
                              hipStream_t stream){
  const float* x   = (const float*)d_in[0];
  const float* cw1 = (const float*)d_in[1];
  const float* cw2 = (const float*)d_in[2];
  const float* lng = (const float*)d_in[3];
  const float* lnb = (const float*)d_in[4];
  const float* ipw = (const float*)d_in[5];
  const float* cvw = (const float*)d_in[6];
  const float* cvb = (const float*)d_in[7];
  const float* xpw = (const float*)d_in[8];
  const float* dtw = (const float*)d_in[9];
  const float* dtb = (const float*)d_in[10];
  const float* alg = (const float*)d_in[11];
  const float* ds  = (const float*)d_in[12];
  const float* ong = (const float*)d_in[13];
  const float* onb = (const float*)d_in[14];
  const float* opw = (const float*)d_in[15];
  float* out = (float*)d_out;
  float* ws = (float*)d_ws;

  float* s_   = ws;                          // 384
  float* a_   = s_  + 384;                   // 384
  float* xi_  = a_  + 384;                   // 884736
  float* xc_  = xi_ + 884736;                // 1769472 (reused: hloc+P after conv)
  float* z_   = xc_ + 1769472;               // 1769472
  float* xo_  = z_  + 1769472;               // 1769472
  _Float16* dtT_ = (_Float16*)(xo_ + 1769472);   // 7077888 halves
  _Float16* uT_  = dtT_ + 7077888;               // 3538944 halves
  float* BC_  = (float*)(uT_ + 3538944);     // 1179648 (fused B+C, t-major)
  float* yB_  = BC_ + 1179648;               // 7077888
  float* ot_  = yB_ + 7077888;               // 884736 (reused: Hinit before merge)

  float* hloc_ = xc_;                        // 786432
  float* Pb_   = xc_ + 786432;               // 786432
  float* Hin_  = ot_;                        // 786432

  k_mean  <<<Bn*Cc, 256, 0, stream>>>(x, s_);
  k_ca    <<<1, 384, 0, stream>>>(s_, cw1, cw2, a_);
  k_xca   <<<dim3(HW/64, Cc/32, Bn), 256, 0, stream>>>(x, a_, xi_);
  k_lnproj<<<Bn*HW/32, 256, 0, stream>>>(xi_, lng, lnb, ipw, xc_, z_);
  k_conv  <<<(Bn*HW*(Dd/4))/256, 256, 0, stream>>>(xc_, cvw, cvb, xo_);
  k_xdbl  <<<Bn*2*(Ll/32), 256, 0, stream>>>(xo_, xpw, dtw, dtb, dtT_, uT_, BC_);
  k_scan1 <<<Bn*Kk*NCH*3, 256, 0, stream>>>(dtT_, uT_, BC_, alg, hloc_, Pb_);
  k_comb  <<<(Bn*Kk*Dd*NS)/256, 256, 0, stream>>>(hloc_, Pb_, Hin_);
  k_scan2 <<<Bn*Kk*NCH*3, 256, 0, stream>>>(dtT_, uT_, BC_, alg, ds, Hin_, yB_);
  k_merge <<<Bn*HW/32, 256, 0, stream>>>(yB_, ong, onb, z_, opw, xi_, ot_);
  k_outT  <<<dim3(HW/64, Cc/32, Bn), 256, 0, stream>>>(ot_, out);
}

// Round 5
// 284.221 us; speedup vs baseline: 5.1045x; 1.1130x over previous
//
#include <hip/hip_runtime.h>
#include <math.h>

#define Bn 4
#define Cc 96
#define Hh 48
#define Ww 48
#define HW 2304
#define Dd 192
#define NS 16
#define Kk 4
#define RK 6
#define CD 38   // RK + 2*NS
#define Ll 2304
#define NCH 16
#define CL 144  // Ll / NCH

typedef _Float16 half4 __attribute__((ext_vector_type(4)));
typedef float f4v __attribute__((ext_vector_type(4)));

#define FMA4(A,W,U) { A.x=fmaf(W,U.x,A.x); A.y=fmaf(W,U.y,A.y); A.z=fmaf(W,U.z,A.z); A.w=fmaf(W,U.w,A.w); }

__device__ __forceinline__ float sigmoidf_(float x){ return 1.0f/(1.0f+__expf(-x)); }
__device__ __forceinline__ float siluf_(float x){ return x*sigmoidf_(x); }
__device__ __forceinline__ float softplusf_(float x){ return (x>20.0f)? x : log1pf(__expf(x)); }

// ---- K1a: s[b,c] = mean over HW ----
__global__ __launch_bounds__(256) void k_mean(const float* __restrict__ x, float* __restrict__ s){
  int bc = blockIdx.x;
  const float* p = x + (size_t)bc*HW;
  float acc = 0.f;
  for(int i=threadIdx.x;i<HW;i+=256) acc += p[i];
  __shared__ float red[256];
  red[threadIdx.x]=acc; __syncthreads();
  for(int o=128;o>0;o>>=1){ if(threadIdx.x<o) red[threadIdx.x]+=red[threadIdx.x+o]; __syncthreads(); }
  if(threadIdx.x==0) s[bc]=red[0]*(1.0f/HW);
}

// ---- K1b: a = sigmoid(relu(s@w1^T)@w2^T) ----
__global__ __launch_bounds__(384) void k_ca(const float* __restrict__ s, const float* __restrict__ w1,
                     const float* __restrict__ w2, float* __restrict__ a){
  __shared__ float hid[Bn*RK];
  int tid=threadIdx.x;
  if(tid<Bn*RK){
    int b=tid/RK, r=tid%RK;
    float acc=0.f;
    for(int c=0;c<Cc;c++) acc += s[b*Cc+c]*w1[r*Cc+c];
    hid[tid]=fmaxf(acc,0.f);
  }
  __syncthreads();
  int b=tid/Cc, c=tid%Cc;
  float acc=0.f;
  for(int r=0;r<RK;r++) acc += hid[b*RK+r]*w2[c*RK+r];
  a[tid]=sigmoidf_(acc);
}

// ---- K2: xi[b,pos,c] = x[b,c,pos]*a[b,c]  (tiled transpose) ----
__global__ __launch_bounds__(256) void k_xca(const float* __restrict__ x, const float* __restrict__ a,
                      float* __restrict__ xi){
  __shared__ float tile[32][65];
  int p0 = blockIdx.x*64, c0 = blockIdx.y*32, b = blockIdx.z;
  int pj = threadIdx.x%64, ci = threadIdx.x/64;
  for(int i=0;i<8;i++){
    int c = c0+ci+i*4;
    tile[ci+i*4][pj] = x[((size_t)(b*Cc+c))*HW + p0+pj]*a[b*Cc+c];
  }
  __syncthreads();
  int cl = threadIdx.x%32, pl = threadIdx.x/32;
  for(int i=0;i<8;i++){
    int p = pl + i*8;
    xi[((size_t)(b*HW + p0+p))*Cc + c0+cl] = tile[cl][p];
  }
}

// ---- K3: 32-px tile: LN(96) + in_proj GEMM -> xc, z ----
__global__ __launch_bounds__(256) void k_lnproj(const float* __restrict__ xi,
    const float* __restrict__ g, const float* __restrict__ bta,
    const float* __restrict__ w, float* __restrict__ xc, float* __restrict__ z){
  __shared__ float su[Cc*36];     // t-minor swizzled
  __shared__ float wl[128*97];
  int tid = threadIdx.x;
  int pix0 = blockIdx.x*32;
  #pragma unroll
  for(int i=0;i<3;i++){
    int f4 = tid + 256*i;               // 768 = 32px * 24
    int px = f4/24, c4 = f4%24;
    float4 v = *(const float4*)(xi + (size_t)(pix0+px)*Cc + 4*c4);
    int sw = 4*(c4&7);
    su[(4*c4+0)*36 + (px^sw)] = v.x;
    su[(4*c4+1)*36 + (px^sw)] = v.y;
    su[(4*c4+2)*36 + (px^sw)] = v.z;
    su[(4*c4+3)*36 + (px^sw)] = v.w;
  }
  __syncthreads();
  {
    int px = tid>>3, gg = tid&7;
    float sm=0.f, sq=0.f;
    float vals[12];
    #pragma unroll
    for(int i=0;i<12;i++){
      int d = gg + 8*i;
      float v = su[d*36 + (px ^ (4*((d>>2)&7)))];
      vals[i]=v; sm+=v; sq+=v*v;
    }
    sm += __shfl_xor(sm,1); sq += __shfl_xor(sq,1);
    sm += __shfl_xor(sm,2); sq += __shfl_xor(sq,2);
    sm += __shfl_xor(sm,4); sq += __shfl_xor(sq,4);
    float mean = sm*(1.0f/Cc);
    float var  = sq*(1.0f/Cc) - mean*mean;
    float rs = rsqrtf(var + 1e-5f);
    #pragma unroll
    for(int i=0;i<12;i++){
      int d = gg + 8*i;
      su[d*36 + (px ^ (4*((d>>2)&7)))] = (vals[i]-mean)*rs*g[d] + bta[d];
    }
  }
  __syncthreads();
  int t4 = tid&7, cg = tid>>3;
  for(int p=0;p<3;p++){
    if(p) __syncthreads();
    #pragma unroll
    for(int i=0;i<12;i++){
      int f4 = tid + 256*i;             // 3072 = 128*24
      int r = f4/24, c4 = f4%24;
      *(float4*)(wl + r*97 + 4*c4) = *(const float4*)(w + (size_t)(128*p + r)*Cc + 4*c4);
    }
    __syncthreads();
    float4 a0={0,0,0,0},a1={0,0,0,0},a2={0,0,0,0},a3={0,0,0,0};
    for(int d=0; d<Cc; d++){
      float4 u4 = *(const float4*)(su + d*36 + 4*(t4 ^ ((d>>2)&7)));
      float w0 = wl[(cg+  0)*97 + d];
      float w1 = wl[(cg+ 32)*97 + d];
      float w2 = wl[(cg+ 64)*97 + d];
      float w3 = wl[(cg+ 96)*97 + d];
      FMA4(a0,w0,u4); FMA4(a1,w1,u4); FMA4(a2,w2,u4); FMA4(a3,w3,u4);
    }
    #pragma unroll
    for(int j=0;j<4;j++){
      int c = 128*p + cg + 32*j;
      float4 a = (j==0)?a0:(j==1)?a1:(j==2)?a2:a3;
      #pragma unroll
      for(int q=0;q<4;q++){
        int px = pix0 + 4*t4 + q;
        float vv = (q==0)?a.x:(q==1)?a.y:(q==2)?a.z:a.w;
        if(c < Dd) xc[(size_t)px*Dd + c] = vv;
        else       z [(size_t)px*Dd + (c-Dd)] = vv;
      }
    }
  }
}

// ---- K4: depthwise 3x3 conv SAME + bias + SiLU ----
__global__ __launch_bounds__(256) void k_conv(const float* __restrict__ xc, const float* __restrict__ cw,
                       const float* __restrict__ cb, float* __restrict__ xo){
  int idx = blockIdx.x*256 + threadIdx.x;
  if(idx >= Bn*HW*(Dd/4)) return;
  int d4 = idx % (Dd/4); int pos = (idx/(Dd/4))%HW; int b = idx/((Dd/4)*HW);
  int h = pos/Ww, w = pos%Ww;
  int d0 = d4*4;
  float4 acc = {cb[d0],cb[d0+1],cb[d0+2],cb[d0+3]};
  #pragma unroll
  for(int kh=0;kh<3;kh++){
    int hh=h+kh-1; if(hh<0||hh>=Hh) continue;
    #pragma unroll
    for(int kw=0;kw<3;kw++){
      int ww2=w+kw-1; if(ww2<0||ww2>=Ww) continue;
      float4 v = *(const float4*)(xc + ((size_t)(b*HW + hh*Ww+ww2))*Dd + d0);
      int wi = kh*3+kw;
      acc.x += v.x*cw[(d0+0)*9+wi];
      acc.y += v.y*cw[(d0+1)*9+wi];
      acc.z += v.z*cw[(d0+2)*9+wi];
      acc.w += v.w*cw[(d0+3)*9+wi];
    }
  }
  float4 o; o.x=siluf_(acc.x); o.y=siluf_(acc.y); o.z=siluf_(acc.z); o.w=siluf_(acc.w);
  *(float4*)(xo + ((size_t)(b*HW+pos))*Dd + d0) = o;
}

// ---- K5: 32-t tile, both k's of one order: x_dbl GEMM + dt + streams ----
// fp16 weight tile in LDS (even stride 196, 8-B aligned stores) -> 43.4 KB total -> 3 blocks/CU
__global__ __launch_bounds__(256) void k_xdbl(const float* __restrict__ xconv,
   const float* __restrict__ xpw, const float* __restrict__ dtw,
   const float* __restrict__ dtb, _Float16* __restrict__ dtT,
   _Float16* __restrict__ uT, float* __restrict__ BC){
  __shared__ float su[Dd*36];
  __shared__ _Float16 wl16[CD*196];
  __shared__ float dts[RK*36];
  int tid = threadIdx.x;
  int blk = blockIdx.x;
  int tile = blk % (Ll/32);
  int ord  = (blk/(Ll/32))&1;
  int b    = blk/((Ll/32)*2);
  int t0 = tile*32;
  #pragma unroll
  for(int i=0;i<6;i++){
    int f4 = tid+256*i;                 // 1536 = 32t * 48
    int r = f4/48, c4 = f4%48;
    int t = t0+r;
    int pos = ord ? ((t%Ww)*Ww + t/Ww) : t;
    float4 v = *(const float4*)(xconv + (size_t)(b*HW+pos)*Dd + 4*c4);
    int sw = 4*(c4&7);
    su[(4*c4+0)*36 + (r^sw)] = v.x;
    su[(4*c4+1)*36 + (r^sw)] = v.y;
    su[(4*c4+2)*36 + (r^sw)] = v.z;
    su[(4*c4+3)*36 + (r^sw)] = v.w;
  }
  __syncthreads();
  if(tid < Dd){
    int d = tid;
    _Float16* up = uT + ((size_t)(b*2+ord)*Dd + d)*Ll + t0;
    #pragma unroll
    for(int r4=0;r4<8;r4++){
      float4 v = *(const float4*)(su + d*36 + 4*(r4 ^ ((d>>2)&7)));
      half4 hv; hv[0]=(_Float16)v.x; hv[1]=(_Float16)v.y; hv[2]=(_Float16)v.z; hv[3]=(_Float16)v.w;
      *(half4*)(up + 4*r4) = hv;
    }
  }
  int t4 = tid&7, cg = tid>>3;
  for(int kx=0;kx<2;kx++){
    int k = ord + 2*kx;
    bool rev = (kx==1);
    __syncthreads();
    for(int i=tid;i<CD*48;i+=256){
      int c = i/48, c4 = i%48;
      float4 v = *(const float4*)(xpw + ((size_t)(k*CD+c))*Dd + 4*c4);
      half4 hv; hv[0]=(_Float16)v.x; hv[1]=(_Float16)v.y; hv[2]=(_Float16)v.z; hv[3]=(_Float16)v.w;
      *(half4*)(wl16 + c*196 + 4*c4) = hv;
    }
    __syncthreads();
    float4 a0={0,0,0,0}, a1={0,0,0,0};
    for(int d=0; d<Dd; d++){
      float4 u4 = *(const float4*)(su + d*36 + 4*(t4 ^ ((d>>2)&7)));
      float w0 = (float)wl16[cg*196 + d];
      FMA4(a0,w0,u4);
      if(cg < CD-32){ float w1 = (float)wl16[(cg+32)*196 + d]; FMA4(a1,w1,u4); }
    }
    #pragma unroll
    for(int j=0;j<2;j++){
      if(j==1 && cg>=CD-32) break;
      int c = cg + 32*j;
      float4 a = j? a1 : a0;
      if(c < RK){
        dts[c*36 + 4*t4+0]=a.x; dts[c*36+4*t4+1]=a.y; dts[c*36+4*t4+2]=a.z; dts[c*36+4*t4+3]=a.w;
      } else {
        int nn = c - RK;   // 0..31
        float* dst = BC + ((size_t)(b*Kk+k)*Ll)*32 + nn;
        float av[4] = {a.x,a.y,a.z,a.w};
        #pragma unroll
        for(int q=0;q<4;q++){
          int t = t0 + 4*t4 + q;
          int tq = rev ? (Ll-1-t) : t;
          dst[(size_t)tq*32] = av[q];
        }
      }
    }
    __syncthreads();
    int tl = tid&31, ds8 = tid>>5;
    #pragma unroll 4
    for(int i=0;i<24;i++){
      int d = ds8 + 8*i;
      float acc = dtb[k*Dd + d];
      #pragma unroll
      for(int r=0;r<RK;r++) acc = fmaf(dtw[((size_t)(k*Dd+d))*RK + r], dts[r*36 + tl], acc);
      acc = softplusf_(acc);
      int tq = rev ? (Ll-1-t0-tl) : (t0+tl);
      dtT[((size_t)(b*Kk+k)*Dd + d)*Ll + tq] = (_Float16)acc;
    }
  }
}

// ---- K6a: pass1 — 4 states per lane, no cross-lane ops ----
__global__ __launch_bounds__(256) void k_scan1(const _Float16* __restrict__ dtT,
  const _Float16* __restrict__ uT, const float* __restrict__ BC,
  const float* __restrict__ Alog, float* __restrict__ hloc, float* __restrict__ Pb){
  int blk=blockIdx.x;
  int dblk = blk % 3;
  int ch  = (blk/3)%NCH;
  int k   = (blk/(3*NCH))%Kk;
  int b   = blk/(3*NCH*Kk);
  int tid=threadIdx.x;
  int nq = tid&3, dl = tid>>2;
  int d = dblk*64 + dl;
  f4v An;
  #pragma unroll
  for(int i=0;i<4;i++) An[i] = -__expf(Alog[((size_t)(k*Dd+d))*NS + 4*nq + i]);
  const _Float16* dp = dtT + ((size_t)(b*Kk+k)*Dd + d)*Ll + ch*CL;
  const _Float16* ub = uT  + ((size_t)(b*2+(k&1))*Dd + d)*Ll;
  const float*    bc = BC  + ((size_t)(b*Kk+k)*Ll + ch*CL)*32 + 4*nq;
  bool rev = (k>=2);
  int s0 = ch*CL;
  f4v h = {0,0,0,0};
  float sdt = 0.f;
  for(int tl=0; tl<CL; tl+=4){
    half4 dt4 = *(const half4*)(dp+tl);
    float u[4];
    if(!rev){
      half4 u4 = *(const half4*)(ub + s0+tl);
      u[0]=(float)u4[0]; u[1]=(float)u4[1]; u[2]=(float)u4[2]; u[3]=(float)u4[3];
    } else {
      half4 u4 = *(const half4*)(ub + (Ll-4-s0-tl));
      u[0]=(float)u4[3]; u[1]=(float)u4[2]; u[2]=(float)u4[1]; u[3]=(float)u4[0];
    }
    #pragma unroll
    for(int j=0;j<4;j++){
      f4v Bv = *(const f4v*)(bc + (size_t)(tl+j)*32);
      float dtv = (float)dt4[j];
      sdt += dtv;
      float xB = dtv*u[j];
      #pragma unroll
      for(int i=0;i<4;i++){
        float ae = __expf(dtv*An[i]);
        h[i] = fmaf(h[i], ae, xB*Bv[i]);
      }
    }
  }
  size_t o = (((size_t)(b*Kk+k)*NCH + ch)*Dd + d)*NS + 4*nq;
  *(f4v*)(hloc + o) = h;
  f4v P;
  #pragma unroll
  for(int i=0;i<4;i++) P[i] = __expf(An[i]*sdt);
  *(f4v*)(Pb + o) = P;
}

// ---- K6b: combine ----
__global__ __launch_bounds__(256) void k_comb(const float* __restrict__ hloc,
  const float* __restrict__ Pb, float* __restrict__ Hin){
  int idx = blockIdx.x*256 + threadIdx.x;
  int inner = idx % (Dd*NS);
  int bk = idx / (Dd*NS);
  size_t base = (size_t)bk*NCH*Dd*NS + inner;
  float H = 0.f;
  for(int ch=0; ch<NCH; ch++){
    size_t o = base + (size_t)ch*Dd*NS;
    Hin[o] = H;
    H = Pb[o]*H + hloc[o];
  }
}

// ---- K6c: pass2 — 4 states per lane, depth-2 shuffle off critical path ----
__global__ __launch_bounds__(256) void k_scan2(const _Float16* __restrict__ dtT,
  const _Float16* __restrict__ uT, const float* __restrict__ BC,
  const float* __restrict__ Alog, const float* __restrict__ Ds,
  const float* __restrict__ Hin, float* __restrict__ yB){
  int blk=blockIdx.x;
  int dblk = blk % 3;
  int ch  = (blk/3)%NCH;
  int k   = (blk/(3*NCH))%Kk;
  int b   = blk/(3*NCH*Kk);
  int tid=threadIdx.x;
  int nq = tid&3, dl = tid>>2;
  int d = dblk*64 + dl;
  f4v An;
  #pragma unroll
  for(int i=0;i<4;i++) An[i] = -__expf(Alog[((size_t)(k*Dd+d))*NS + 4*nq + i]);
  float Dv = Ds[k*Dd+d];
  const _Float16* dp = dtT + ((size_t)(b*Kk+k)*Dd + d)*Ll + ch*CL;
  const _Float16* ub = uT  + ((size_t)(b*2+(k&1))*Dd + d)*Ll;
  const float*    bc = BC  + ((size_t)(b*Kk+k)*Ll + ch*CL)*32 + 4*nq;
  float*          yp = yB  + ((size_t)(b*Kk+k)*Ll)*Dd + d;
  bool rev = (k>=2);
  int s0 = ch*CL;
  f4v h = *(const f4v*)(Hin + (((size_t)(b*Kk+k)*NCH + ch)*Dd + d)*NS + 4*nq);
  for(int tl=0; tl<CL; tl+=4){
    half4 dt4 = *(const half4*)(dp+tl);
    float u[4];
    if(!rev){
      half4 u4 = *(const half4*)(ub + s0+tl);
      u[0]=(float)u4[0]; u[1]=(float)u4[1]; u[2]=(float)u4[2]; u[3]=(float)u4[3];
    } else {
      half4 u4 = *(const half4*)(ub + (Ll-4-s0-tl));
      u[0]=(float)u4[3]; u[1]=(float)u4[2]; u[2]=(float)u4[1]; u[3]=(float)u4[0];
    }
    #pragma unroll
    for(int j=0;j<4;j++){
      f4v Bv = *(const f4v*)(bc + (size_t)(tl+j)*32);
      f4v Cv = *(const f4v*)(bc + (size_t)(tl+j)*32 + 16);
      float dtv = (float)dt4[j];
      float xB = dtv*u[j];
      #pragma unroll
      for(int i=0;i<4;i++){
        float ae = __expf(dtv*An[i]);
        h[i] = fmaf(h[i], ae, xB*Bv[i]);
      }
      float p = h[0]*Cv[0];
      p = fmaf(h[1],Cv[1],p); p = fmaf(h[2],Cv[2],p); p = fmaf(h[3],Cv[3],p);
      p += __shfl_xor(p,1); p += __shfl_xor(p,2);
      if(nq==0) yp[(size_t)(s0+tl+j)*Dd] = p + Dv*u[j];
    }
  }
}

// ---- K7: 32-px tile: merge 4 dirs + LN(192) + gate + out_proj GEMM + residual ----
__global__ __launch_bounds__(256) void k_merge(const float* __restrict__ yB,
  const float* __restrict__ og, const float* __restrict__ ob,
  const float* __restrict__ zB, const float* __restrict__ opw,
  const float* __restrict__ xi, float* __restrict__ ot){
  __shared__ float yv[Dd*36];
  __shared__ float wl[48*193];
  int tid = threadIdx.x;
  int pix0 = blockIdx.x*32;
  int b = pix0/HW;
  int pos0 = pix0%HW;
  size_t ybase = (size_t)b*Kk*Ll*Dd;
  #pragma unroll
  for(int i=0;i<6;i++){
    int f4 = tid+256*i;                 // 1536 = 32px*48
    int r = f4/48, c4 = f4%48;
    int pos = pos0+r;
    int lwh = (pos%Ww)*Ww + pos/Ww;
    float4 v0 = *(const float4*)(yB + ybase + ((size_t)(0*Ll) + pos)*Dd + 4*c4);
    float4 v2 = *(const float4*)(yB + ybase + ((size_t)(2*Ll) + (Ll-1-pos))*Dd + 4*c4);
    float4 v1 = *(const float4*)(yB + ybase + ((size_t)(1*Ll) + lwh)*Dd + 4*c4);
    float4 v3 = *(const float4*)(yB + ybase + ((size_t)(3*Ll) + (Ll-1-lwh))*Dd + 4*c4);
    float4 v; v.x=v0.x+v1.x+v2.x+v3.x; v.y=v0.y+v1.y+v2.y+v3.y;
    v.z=v0.z+v1.z+v2.z+v3.z; v.w=v0.w+v1.w+v2.w+v3.w;
    int sw = 4*(c4&7);
    yv[(4*c4+0)*36 + (r^sw)] = v.x;
    yv[(4*c4+1)*36 + (r^sw)] = v.y;
    yv[(4*c4+2)*36 + (r^sw)] = v.z;
    yv[(4*c4+3)*36 + (r^sw)] = v.w;
  }
  __syncthreads();
  {
    int px = tid>>3, gg = tid&7;
    float sm=0.f, sq=0.f;
    float vals[24];
    #pragma unroll
    for(int i=0;i<24;i++){
      int d = gg + 8*i;
      float v = yv[d*36 + (px ^ (4*((d>>2)&7)))];
      vals[i]=v; sm+=v; sq+=v*v;
    }
    sm += __shfl_xor(sm,1); sq += __shfl_xor(sq,1);
    sm += __shfl_xor(sm,2); sq += __shfl_xor(sq,2);
    sm += __shfl_xor(sm,4); sq += __shfl_xor(sq,4);
    float mean = sm*(1.0f/Dd);
    float var  = sq*(1.0f/Dd) - mean*mean;
    float rs = rsqrtf(var + 1e-5f);
    #pragma unroll
    for(int i=0;i<24;i++){
      int d = gg + 8*i;
      float zv = zB[(size_t)(pix0+px)*Dd + d];
      yv[d*36 + (px ^ (4*((d>>2)&7)))] = ((vals[i]-mean)*rs*og[d] + ob[d]) * siluf_(zv);
    }
  }
  __syncthreads();
  int t4 = tid&7, cg = tid>>3;
  for(int p=0;p<2;p++){
    if(p) __syncthreads();
    for(int i=tid;i<48*48;i+=256){
      int c=i/48, c4=i%48;
      *(float4*)(wl + c*193 + 4*c4) = *(const float4*)(opw + (size_t)(48*p+c)*Dd + 4*c4);
    }
    __syncthreads();
    float4 a0={0,0,0,0}, a1={0,0,0,0};
    for(int d=0;d<Dd;d++){
      float4 u4 = *(const float4*)(yv + d*36 + 4*(t4 ^ ((d>>2)&7)));
      float w0 = wl[cg*193+d];
      FMA4(a0,w0,u4);
      if(cg<16){ float w1 = wl[(cg+32)*193+d]; FMA4(a1,w1,u4); }
    }
    #pragma unroll
    for(int j=0;j<2;j++){
      if(j==1 && cg>=16) break;
      int c = 48*p + cg + 32*j;
      float4 a = j?a1:a0;
      #pragma unroll
      for(int q=0;q<4;q++){
        int px = pix0 + 4*t4 + q;
        float vv = (q==0)?a.x:(q==1)?a.y:(q==2)?a.z:a.w;
        ot[(size_t)px*Cc + c] = vv + xi[(size_t)px*Cc + c];
      }
    }
  }
}

// ---- K8: (B,HW,C) -> (B,C,HW) tiled transpose ----
__global__ __launch_bounds__(256) void k_outT(const float* __restrict__ ot, float* __restrict__ out){
  __shared__ float tile[64][33];
  int p0=blockIdx.x*64, c0=blockIdx.y*32, b=blockIdx.z;
  int cl=threadIdx.x%32, pl=threadIdx.x/32;
  for(int i=0;i<8;i++){
    int p = pl+i*8;
    tile[p][cl] = ot[((size_t)(b*HW+p0+p))*Cc + c0+cl];
  }
  __syncthreads();
  int pj=threadIdx.x%64, ci=threadIdx.x/64;
  for(int i=0;i<8;i++){
    int c=ci+i*4;
    out[((size_t)(b*Cc+c0+c))*HW + p0+pj] = tile[pj][c];
  }
}

extern "C" void kernel_launch(void* const* d_in, const int* in_sizes, int n_in,
                              void* d_out, int out_size, void* d_ws, size_t ws_size,
                              hipStream_t stream){
  const float* x   = (const float*)d_in[0];
  const float* cw1 = (const float*)d_in[1];
  const float* cw2 = (const float*)d_in[2];
  const float* lng = (const float*)d_in[3];
  const float* lnb = (const float*)d_in[4];
  const float* ipw = (const float*)d_in[5];
  const float* cvw = (const float*)d_in[6];
  const float* cvb = (const float*)d_in[7];
  const float* xpw = (const float*)d_in[8];
  const float* dtw = (const float*)d_in[9];
  const float* dtb = (const float*)d_in[10];
  const float* alg = (const float*)d_in[11];
  const float* ds  = (const float*)d_in[12];
  const float* ong = (const float*)d_in[13];
  const float* onb = (const float*)d_in[14];
  const float* opw = (const float*)d_in[15];
  float* out = (float*)d_out;
  float* ws = (float*)d_ws;

  float* s_   = ws;                          // 384
  float* a_   = s_  + 384;                   // 384
  float* xi_  = a_  + 384;                   // 884736
  float* xc_  = xi_ + 884736;                // 1769472 (reused: hloc+P after conv)
  float* z_   = xc_ + 1769472;               // 1769472
  float* xo_  = z_  + 1769472;               // 1769472
  _Float16* dtT_ = (_Float16*)(xo_ + 1769472);   // 7077888 halves
  _Float16* uT_  = dtT_ + 7077888;               // 3538944 halves
  float* BC_  = (float*)(uT_ + 3538944);     // 1179648 (fused B+C, t-major)
  float* yB_  = BC_ + 1179648;               // 7077888
  float* ot_  = yB_ + 7077888;               // 884736 (reused: Hinit before merge)

  float* hloc_ = xc_;                        // 786432
  float* Pb_   = xc_ + 786432;               // 786432
  float* Hin_  = ot_;                        // 786432

  k_mean  <<<Bn*Cc, 256, 0, stream>>>(x, s_);
  k_ca    <<<1, 384, 0, stream>>>(s_, cw1, cw2, a_);
  k_xca   <<<dim3(HW/64, Cc/32, Bn), 256, 0, stream>>>(x, a_, xi_);
  k_lnproj<<<Bn*HW/32, 256, 0, stream>>>(xi_, lng, lnb, ipw, xc_, z_);
  k_conv  <<<(Bn*HW*(Dd/4))/256, 256, 0, stream>>>(xc_, cvw, cvb, xo_);
  k_xdbl  <<<Bn*2*(Ll/32), 256, 0, stream>>>(xo_, xpw, dtw, dtb, dtT_, uT_, BC_);
  k_scan1 <<<Bn*Kk*NCH*3, 256, 0, stream>>>(dtT_, uT_, BC_, alg, hloc_, Pb_);
  k_comb  <<<(Bn*Kk*Dd*NS)/256, 256, 0, stream>>>(hloc_, Pb_, Hin_);
  k_scan2 <<<Bn*Kk*NCH*3, 256, 0, stream>>>(dtT_, uT_, BC_, alg, ds, Hin_, yB_);
  k_merge <<<Bn*HW/32, 256, 0, stream>>>(yB_, ong, onb, z_, opw, xi_, ot_);
  k_outT  <<<dim3(HW/64, Cc/32, Bn), 256, 0, stream>>>(ot_, out);
}

// Round 6
// 273.225 us; speedup vs baseline: 5.3099x; 1.0402x over previous
//
#include <hip/hip_runtime.h>
#include <math.h>

#define Bn 4
#define Cc 96
#define Hh 48
#define Ww 48
#define HW 2304
#define Dd 192
#define NS 16
#define Kk 4
#define RK 6
#define CD 38   // RK + 2*NS
#define Ll 2304
#define NCH 16
#define CL 144  // Ll / NCH

typedef _Float16 half4 __attribute__((ext_vector_type(4)));
typedef _Float16 half8 __attribute__((ext_vector_type(8)));
typedef float f4v __attribute__((ext_vector_type(4)));

#define FMA4(A,W,U) { A.x=fmaf(W,U.x,A.x); A.y=fmaf(W,U.y,A.y); A.z=fmaf(W,U.z,A.z); A.w=fmaf(W,U.w,A.w); }

__device__ __forceinline__ float sigmoidf_(float x){ return 1.0f/(1.0f+__expf(-x)); }
__device__ __forceinline__ float siluf_(float x){ return x*sigmoidf_(x); }
__device__ __forceinline__ float softplusf_(float x){ return (x>20.0f)? x : log1pf(__expf(x)); }

// ---- K1a: s[b,c] = mean over HW ----
__global__ __launch_bounds__(256) void k_mean(const float* __restrict__ x, float* __restrict__ s){
  int bc = blockIdx.x;
  const float* p = x + (size_t)bc*HW;
  float acc = 0.f;
  for(int i=threadIdx.x;i<HW;i+=256) acc += p[i];
  __shared__ float red[256];
  red[threadIdx.x]=acc; __syncthreads();
  for(int o=128;o>0;o>>=1){ if(threadIdx.x<o) red[threadIdx.x]+=red[threadIdx.x+o]; __syncthreads(); }
  if(threadIdx.x==0) s[bc]=red[0]*(1.0f/HW);
}

// ---- K1b: a = sigmoid(relu(s@w1^T)@w2^T) ----
__global__ __launch_bounds__(384) void k_ca(const float* __restrict__ s, const float* __restrict__ w1,
                     const float* __restrict__ w2, float* __restrict__ a){
  __shared__ float hid[Bn*RK];
  int tid=threadIdx.x;
  if(tid<Bn*RK){
    int b=tid/RK, r=tid%RK;
    float acc=0.f;
    for(int c=0;c<Cc;c++) acc += s[b*Cc+c]*w1[r*Cc+c];
    hid[tid]=fmaxf(acc,0.f);
  }
  __syncthreads();
  int b=tid/Cc, c=tid%Cc;
  float acc=0.f;
  for(int r=0;r<RK;r++) acc += hid[b*RK+r]*w2[c*RK+r];
  a[tid]=sigmoidf_(acc);
}

// ---- K2: xi[b,pos,c] = x[b,c,pos]*a[b,c]  (tiled transpose) ----
__global__ __launch_bounds__(256) void k_xca(const float* __restrict__ x, const float* __restrict__ a,
                      float* __restrict__ xi){
  __shared__ float tile[32][65];
  int p0 = blockIdx.x*64, c0 = blockIdx.y*32, b = blockIdx.z;
  int pj = threadIdx.x%64, ci = threadIdx.x/64;
  for(int i=0;i<8;i++){
    int c = c0+ci+i*4;
    tile[ci+i*4][pj] = x[((size_t)(b*Cc+c))*HW + p0+pj]*a[b*Cc+c];
  }
  __syncthreads();
  int cl = threadIdx.x%32, pl = threadIdx.x/32;
  for(int i=0;i<8;i++){
    int p = pl + i*8;
    xi[((size_t)(b*HW + p0+p))*Cc + c0+cl] = tile[cl][p];
  }
}

// ---- K3: 32-px tile, phase-split over blockIdx.y: LN(96) + in_proj GEMM -> xc, z ----
// fp16 weight tile (stride 104 halves = 208 B rows: 16B-aligned chunks, conflict-free)
__global__ __launch_bounds__(256) void k_lnproj(const float* __restrict__ xi,
    const float* __restrict__ g, const float* __restrict__ bta,
    const float* __restrict__ w, float* __restrict__ xc, float* __restrict__ z){
  __shared__ float su[Cc*36];     // t-minor swizzled, f32
  __shared__ _Float16 wl16[128*104];
  int tid = threadIdx.x;
  int pix0 = blockIdx.x*32;
  int p = blockIdx.y;             // phase 0..2 (c-range 128p..128p+127)
  #pragma unroll
  for(int i=0;i<3;i++){
    int f4 = tid + 256*i;               // 768 = 32px * 24
    int px = f4/24, c4 = f4%24;
    float4 v = *(const float4*)(xi + (size_t)(pix0+px)*Cc + 4*c4);
    int sw = 4*(c4&7);
    su[(4*c4+0)*36 + (px^sw)] = v.x;
    su[(4*c4+1)*36 + (px^sw)] = v.y;
    su[(4*c4+2)*36 + (px^sw)] = v.z;
    su[(4*c4+3)*36 + (px^sw)] = v.w;
  }
  __syncthreads();
  {
    int px = tid>>3, gg = tid&7;
    float sm=0.f, sq=0.f;
    float vals[12];
    #pragma unroll
    for(int i=0;i<12;i++){
      int d = gg + 8*i;
      float v = su[d*36 + (px ^ (4*((d>>2)&7)))];
      vals[i]=v; sm+=v; sq+=v*v;
    }
    sm += __shfl_xor(sm,1); sq += __shfl_xor(sq,1);
    sm += __shfl_xor(sm,2); sq += __shfl_xor(sq,2);
    sm += __shfl_xor(sm,4); sq += __shfl_xor(sq,4);
    float mean = sm*(1.0f/Cc);
    float var  = sq*(1.0f/Cc) - mean*mean;
    float rs = rsqrtf(var + 1e-5f);
    #pragma unroll
    for(int i=0;i<12;i++){
      int d = gg + 8*i;
      su[d*36 + (px ^ (4*((d>>2)&7)))] = (vals[i]-mean)*rs*g[d] + bta[d];
    }
  }
  // stage this phase's 128 weight rows as fp16
  #pragma unroll
  for(int i=0;i<12;i++){
    int f4 = tid + 256*i;             // 3072 = 128*24
    int r = f4/24, c4 = f4%24;
    float4 v = *(const float4*)(w + (size_t)(128*p + r)*Cc + 4*c4);
    half4 hv; hv[0]=(_Float16)v.x; hv[1]=(_Float16)v.y; hv[2]=(_Float16)v.z; hv[3]=(_Float16)v.w;
    *(half4*)(wl16 + r*104 + 4*c4) = hv;
  }
  __syncthreads();
  int t4 = tid&7, cg = tid>>3;
  float4 a0={0,0,0,0},a1={0,0,0,0},a2={0,0,0,0},a3={0,0,0,0};
  for(int d0=0; d0<Cc; d0+=8){
    half8 w0v = *(const half8*)(wl16 + (cg+  0)*104 + d0);
    half8 w1v = *(const half8*)(wl16 + (cg+ 32)*104 + d0);
    half8 w2v = *(const half8*)(wl16 + (cg+ 64)*104 + d0);
    half8 w3v = *(const half8*)(wl16 + (cg+ 96)*104 + d0);
    #pragma unroll
    for(int j=0;j<8;j++){
      int d = d0+j;
      float4 u4 = *(const float4*)(su + d*36 + 4*(t4 ^ ((d>>2)&7)));
      FMA4(a0,(float)w0v[j],u4);
      FMA4(a1,(float)w1v[j],u4);
      FMA4(a2,(float)w2v[j],u4);
      FMA4(a3,(float)w3v[j],u4);
    }
  }
  #pragma unroll
  for(int j=0;j<4;j++){
    int c = 128*p + cg + 32*j;
    float4 a = (j==0)?a0:(j==1)?a1:(j==2)?a2:a3;
    #pragma unroll
    for(int q=0;q<4;q++){
      int px = pix0 + 4*t4 + q;
      float vv = (q==0)?a.x:(q==1)?a.y:(q==2)?a.z:a.w;
      if(c < Dd) xc[(size_t)px*Dd + c] = vv;
      else       z [(size_t)px*Dd + (c-Dd)] = vv;
    }
  }
}

// ---- K4: depthwise 3x3 conv SAME + bias + SiLU ----
__global__ __launch_bounds__(256) void k_conv(const float* __restrict__ xc, const float* __restrict__ cw,
                       const float* __restrict__ cb, float* __restrict__ xo){
  int idx = blockIdx.x*256 + threadIdx.x;
  if(idx >= Bn*HW*(Dd/4)) return;
  int d4 = idx % (Dd/4); int pos = (idx/(Dd/4))%HW; int b = idx/((Dd/4)*HW);
  int h = pos/Ww, w = pos%Ww;
  int d0 = d4*4;
  float4 acc = {cb[d0],cb[d0+1],cb[d0+2],cb[d0+3]};
  #pragma unroll
  for(int kh=0;kh<3;kh++){
    int hh=h+kh-1; if(hh<0||hh>=Hh) continue;
    #pragma unroll
    for(int kw=0;kw<3;kw++){
      int ww2=w+kw-1; if(ww2<0||ww2>=Ww) continue;
      float4 v = *(const float4*)(xc + ((size_t)(b*HW + hh*Ww+ww2))*Dd + d0);
      int wi = kh*3+kw;
      acc.x += v.x*cw[(d0+0)*9+wi];
      acc.y += v.y*cw[(d0+1)*9+wi];
      acc.z += v.z*cw[(d0+2)*9+wi];
      acc.w += v.w*cw[(d0+3)*9+wi];
    }
  }
  float4 o; o.x=siluf_(acc.x); o.y=siluf_(acc.y); o.z=siluf_(acc.z); o.w=siluf_(acc.w);
  *(float4*)(xo + ((size_t)(b*HW+pos))*Dd + d0) = o;
}

// ---- K5: 32-t tile, ONE k per block: x_dbl GEMM + dt + streams ----
// su fp16 (stride 40 halves), weights fp16 (stride 200 halves = 400 B, aligned+conflict-free)
// LDS ~31.4 KB -> 5 blocks/CU; grid 1152 fully co-resident
__global__ __launch_bounds__(256) void k_xdbl(const float* __restrict__ xconv,
   const float* __restrict__ xpw, const float* __restrict__ dtw,
   const float* __restrict__ dtb, _Float16* __restrict__ dtT,
   _Float16* __restrict__ uT, float* __restrict__ BC){
  __shared__ _Float16 su[Dd*40];
  __shared__ _Float16 wl16[CD*200];
  __shared__ float dts[RK*36];
  int tid = threadIdx.x;
  int blk = blockIdx.x;
  int tile = blk % (Ll/32);
  int k    = (blk/(Ll/32))%Kk;
  int b    = blk/((Ll/32)*Kk);
  int ord  = k&1;
  bool rev = (k>=2);
  int t0 = tile*32;
  // stage activation tile transposed+swizzled, fp16
  #pragma unroll
  for(int i=0;i<6;i++){
    int f4 = tid+256*i;                 // 1536 = 32t * 48
    int r = f4/48, c4 = f4%48;
    int t = t0+r;
    int pos = ord ? ((t%Ww)*Ww + t/Ww) : t;
    float4 v = *(const float4*)(xconv + (size_t)(b*HW+pos)*Dd + 4*c4);
    int sw = 4*(c4&7);
    su[(4*c4+0)*40 + (r^sw)] = (_Float16)v.x;
    su[(4*c4+1)*40 + (r^sw)] = (_Float16)v.y;
    su[(4*c4+2)*40 + (r^sw)] = (_Float16)v.z;
    su[(4*c4+3)*40 + (r^sw)] = (_Float16)v.w;
  }
  // stage weights for this k as fp16
  for(int i=tid;i<CD*48;i+=256){
    int c = i/48, c4 = i%48;
    float4 v = *(const float4*)(xpw + ((size_t)(k*CD+c))*Dd + 4*c4);
    half4 hv; hv[0]=(_Float16)v.x; hv[1]=(_Float16)v.y; hv[2]=(_Float16)v.z; hv[3]=(_Float16)v.w;
    *(half4*)(wl16 + c*200 + 4*c4) = hv;
  }
  __syncthreads();
  // uT stream (only k<2; k=0/1 cover the two scan orders)
  if(k<2 && tid < Dd){
    int d = tid;
    _Float16* up = uT + ((size_t)(b*2+ord)*Dd + d)*Ll + t0;
    #pragma unroll
    for(int r4=0;r4<8;r4++){
      half4 hv = *(const half4*)(su + d*40 + 4*(r4 ^ ((d>>2)&7)));
      *(half4*)(up + 4*r4) = hv;
    }
  }
  int t4 = tid&7, cg = tid>>3;
  float4 a0={0,0,0,0}, a1={0,0,0,0};
  for(int d0=0; d0<Dd; d0+=8){
    half8 wv0 = *(const half8*)(wl16 + cg*200 + d0);
    half8 wv1;
    if(cg < CD-32) wv1 = *(const half8*)(wl16 + (cg+32)*200 + d0);
    #pragma unroll
    for(int j=0;j<8;j++){
      int d = d0+j;
      half4 uh = *(const half4*)(su + d*40 + 4*(t4 ^ ((d>>2)&7)));
      float4 u4; u4.x=(float)uh[0]; u4.y=(float)uh[1]; u4.z=(float)uh[2]; u4.w=(float)uh[3];
      float w0=(float)wv0[j];
      FMA4(a0,w0,u4);
      if(cg < CD-32){ float w1=(float)wv1[j]; FMA4(a1,w1,u4); }
    }
  }
  #pragma unroll
  for(int j=0;j<2;j++){
    if(j==1 && cg>=CD-32) break;
    int c = cg + 32*j;
    float4 a = j? a1 : a0;
    if(c < RK){
      dts[c*36 + 4*t4+0]=a.x; dts[c*36+4*t4+1]=a.y; dts[c*36+4*t4+2]=a.z; dts[c*36+4*t4+3]=a.w;
    } else {
      int nn = c - RK;   // 0..31
      float* dst = BC + ((size_t)(b*Kk+k)*Ll)*32 + nn;
      float av[4] = {a.x,a.y,a.z,a.w};
      #pragma unroll
      for(int q=0;q<4;q++){
        int t = t0 + 4*t4 + q;
        int tq = rev ? (Ll-1-t) : t;
        dst[(size_t)tq*32] = av[q];
      }
    }
  }
  __syncthreads();
  int tl = tid&31, ds8 = tid>>5;
  #pragma unroll 4
  for(int i=0;i<24;i++){
    int d = ds8 + 8*i;
    float acc = dtb[k*Dd + d];
    #pragma unroll
    for(int r=0;r<RK;r++) acc = fmaf(dtw[((size_t)(k*Dd+d))*RK + r], dts[r*36 + tl], acc);
    acc = softplusf_(acc);
    int tq = rev ? (Ll-1-t0-tl) : (t0+tl);
    dtT[((size_t)(b*Kk+k)*Dd + d)*Ll + tq] = (_Float16)acc;
  }
}

// ---- K6a: pass1 — 4 states per lane, no cross-lane ops ----
__global__ __launch_bounds__(256) void k_scan1(const _Float16* __restrict__ dtT,
  const _Float16* __restrict__ uT, const float* __restrict__ BC,
  const float* __restrict__ Alog, float* __restrict__ hloc, float* __restrict__ Pb){
  int blk=blockIdx.x;
  int dblk = blk % 3;
  int ch  = (blk/3)%NCH;
  int k   = (blk/(3*NCH))%Kk;
  int b   = blk/(3*NCH*Kk);
  int tid=threadIdx.x;
  int nq = tid&3, dl = tid>>2;
  int d = dblk*64 + dl;
  f4v An;
  #pragma unroll
  for(int i=0;i<4;i++) An[i] = -__expf(Alog[((size_t)(k*Dd+d))*NS + 4*nq + i]);
  const _Float16* dp = dtT + ((size_t)(b*Kk+k)*Dd + d)*Ll + ch*CL;
  const _Float16* ub = uT  + ((size_t)(b*2+(k&1))*Dd + d)*Ll;
  const float*    bc = BC  + ((size_t)(b*Kk+k)*Ll + ch*CL)*32 + 4*nq;
  bool rev = (k>=2);
  int s0 = ch*CL;
  f4v h = {0,0,0,0};
  float sdt = 0.f;
  for(int tl=0; tl<CL; tl+=4){
    half4 dt4 = *(const half4*)(dp+tl);
    float u[4];
    if(!rev){
      half4 u4 = *(const half4*)(ub + s0+tl);
      u[0]=(float)u4[0]; u[1]=(float)u4[1]; u[2]=(float)u4[2]; u[3]=(float)u4[3];
    } else {
      half4 u4 = *(const half4*)(ub + (Ll-4-s0-tl));
      u[0]=(float)u4[3]; u[1]=(float)u4[2]; u[2]=(float)u4[1]; u[3]=(float)u4[0];
    }
    #pragma unroll
    for(int j=0;j<4;j++){
      f4v Bv = *(const f4v*)(bc + (size_t)(tl+j)*32);
      float dtv = (float)dt4[j];
      sdt += dtv;
      float xB = dtv*u[j];
      #pragma unroll
      for(int i=0;i<4;i++){
        float ae = __expf(dtv*An[i]);
        h[i] = fmaf(h[i], ae, xB*Bv[i]);
      }
    }
  }
  size_t o = (((size_t)(b*Kk+k)*NCH + ch)*Dd + d)*NS + 4*nq;
  *(f4v*)(hloc + o) = h;
  f4v P;
  #pragma unroll
  for(int i=0;i<4;i++) P[i] = __expf(An[i]*sdt);
  *(f4v*)(Pb + o) = P;
}

// ---- K6b: combine ----
__global__ __launch_bounds__(256) void k_comb(const float* __restrict__ hloc,
  const float* __restrict__ Pb, float* __restrict__ Hin){
  int idx = blockIdx.x*256 + threadIdx.x;
  int inner = idx % (Dd*NS);
  int bk = idx / (Dd*NS);
  size_t base = (size_t)bk*NCH*Dd*NS + inner;
  float H = 0.f;
  for(int ch=0; ch<NCH; ch++){
    size_t o = base + (size_t)ch*Dd*NS;
    Hin[o] = H;
    H = Pb[o]*H + hloc[o];
  }
}

// ---- K6c: pass2 — 4 states per lane, depth-2 shuffle off critical path ----
__global__ __launch_bounds__(256) void k_scan2(const _Float16* __restrict__ dtT,
  const _Float16* __restrict__ uT, const float* __restrict__ BC,
  const float* __restrict__ Alog, const float* __restrict__ Ds,
  const float* __restrict__ Hin, float* __restrict__ yB){
  int blk=blockIdx.x;
  int dblk = blk % 3;
  int ch  = (blk/3)%NCH;
  int k   = (blk/(3*NCH))%Kk;
  int b   = blk/(3*NCH*Kk);
  int tid=threadIdx.x;
  int nq = tid&3, dl = tid>>2;
  int d = dblk*64 + dl;
  f4v An;
  #pragma unroll
  for(int i=0;i<4;i++) An[i] = -__expf(Alog[((size_t)(k*Dd+d))*NS + 4*nq + i]);
  float Dv = Ds[k*Dd+d];
  const _Float16* dp = dtT + ((size_t)(b*Kk+k)*Dd + d)*Ll + ch*CL;
  const _Float16* ub = uT  + ((size_t)(b*2+(k&1))*Dd + d)*Ll;
  const float*    bc = BC  + ((size_t)(b*Kk+k)*Ll + ch*CL)*32 + 4*nq;
  float*          yp = yB  + ((size_t)(b*Kk+k)*Ll)*Dd + d;
  bool rev = (k>=2);
  int s0 = ch*CL;
  f4v h = *(const f4v*)(Hin + (((size_t)(b*Kk+k)*NCH + ch)*Dd + d)*NS + 4*nq);
  for(int tl=0; tl<CL; tl+=4){
    half4 dt4 = *(const half4*)(dp+tl);
    float u[4];
    if(!rev){
      half4 u4 = *(const half4*)(ub + s0+tl);
      u[0]=(float)u4[0]; u[1]=(float)u4[1]; u[2]=(float)u4[2]; u[3]=(float)u4[3];
    } else {
      half4 u4 = *(const half4*)(ub + (Ll-4-s0-tl));
      u[0]=(float)u4[3]; u[1]=(float)u4[2]; u[2]=(float)u4[1]; u[3]=(float)u4[0];
    }
    #pragma unroll
    for(int j=0;j<4;j++){
      f4v Bv = *(const f4v*)(bc + (size_t)(tl+j)*32);
      f4v Cv = *(const f4v*)(bc + (size_t)(tl+j)*32 + 16);
      float dtv = (float)dt4[j];
      float xB = dtv*u[j];
      #pragma unroll
      for(int i=0;i<4;i++){
        float ae = __expf(dtv*An[i]);
        h[i] = fmaf(h[i], ae, xB*Bv[i]);
      }
      float p = h[0]*Cv[0];
      p = fmaf(h[1],Cv[1],p); p = fmaf(h[2],Cv[2],p); p = fmaf(h[3],Cv[3],p);
      p += __shfl_xor(p,1); p += __shfl_xor(p,2);
      if(nq==0) yp[(size_t)(s0+tl+j)*Dd] = p + Dv*u[j];
    }
  }
}

// ---- K7: 32-px tile: merge 4 dirs + LN(192) + gate + out_proj GEMM + residual ----
__global__ __launch_bounds__(256) void k_merge(const float* __restrict__ yB,
  const float* __restrict__ og, const float* __restrict__ ob,
  const float* __restrict__ zB, const float* __restrict__ opw,
  const float* __restrict__ xi, float* __restrict__ ot){
  __shared__ float yv[Dd*36];
  __shared__ float wl[48*193];
  int tid = threadIdx.x;
  int pix0 = blockIdx.x*32;
  int b = pix0/HW;
  int pos0 = pix0%HW;
  size_t ybase = (size_t)b*Kk*Ll*Dd;
  #pragma unroll
  for(int i=0;i<6;i++){
    int f4 = tid+256*i;                 // 1536 = 32px*48
    int r = f4/48, c4 = f4%48;
    int pos = pos0+r;
    int lwh = (pos%Ww)*Ww + pos/Ww;
    float4 v0 = *(const float4*)(yB + ybase + ((size_t)(0*Ll) + pos)*Dd + 4*c4);
    float4 v2 = *(const float4*)(yB + ybase + ((size_t)(2*Ll) + (Ll-1-pos))*Dd + 4*c4);
    float4 v1 = *(const float4*)(yB + ybase + ((size_t)(1*Ll) + lwh)*Dd + 4*c4);
    float4 v3 = *(const float4*)(yB + ybase + ((size_t)(3*Ll) + (Ll-1-lwh))*Dd + 4*c4);
    float4 v; v.x=v0.x+v1.x+v2.x+v3.x; v.y=v0.y+v1.y+v2.y+v3.y;
    v.z=v0.z+v1.z+v2.z+v3.z; v.w=v0.w+v1.w+v2.w+v3.w;
    int sw = 4*(c4&7);
    yv[(4*c4+0)*36 + (r^sw)] = v.x;
    yv[(4*c4+1)*36 + (r^sw)] = v.y;
    yv[(4*c4+2)*36 + (r^sw)] = v.z;
    yv[(4*c4+3)*36 + (r^sw)] = v.w;
  }
  __syncthreads();
  {
    int px = tid>>3, gg = tid&7;
    float sm=0.f, sq=0.f;
    float vals[24];
    #pragma unroll
    for(int i=0;i<24;i++){
      int d = gg + 8*i;
      float v = yv[d*36 + (px ^ (4*((d>>2)&7)))];
      vals[i]=v; sm+=v; sq+=v*v;
    }
    sm += __shfl_xor(sm,1); sq += __shfl_xor(sq,1);
    sm += __shfl_xor(sm,2); sq += __shfl_xor(sq,2);
    sm += __shfl_xor(sm,4); sq += __shfl_xor(sq,4);
    float mean = sm*(1.0f/Dd);
    float var  = sq*(1.0f/Dd) - mean*mean;
    float rs = rsqrtf(var + 1e-5f);
    #pragma unroll
    for(int i=0;i<24;i++){
      int d = gg + 8*i;
      float zv = zB[(size_t)(pix0+px)*Dd + d];
      yv[d*36 + (px ^ (4*((d>>2)&7)))] = ((vals[i]-mean)*rs*og[d] + ob[d]) * siluf_(zv);
    }
  }
  __syncthreads();
  int t4 = tid&7, cg = tid>>3;
  for(int p=0;p<2;p++){
    if(p) __syncthreads();
    for(int i=tid;i<48*48;i+=256){
      int c=i/48, c4=i%48;
      *(float4*)(wl + c*193 + 4*c4) = *(const float4*)(opw + (size_t)(48*p+c)*Dd + 4*c4);
    }
    __syncthreads();
    float4 a0={0,0,0,0}, a1={0,0,0,0};
    for(int d=0;d<Dd;d++){
      float4 u4 = *(const float4*)(yv + d*36 + 4*(t4 ^ ((d>>2)&7)));
      float w0 = wl[cg*193+d];
      FMA4(a0,w0,u4);
      if(cg<16){ float w1 = wl[(cg+32)*193+d]; FMA4(a1,w1,u4); }
    }
    #pragma unroll
    for(int j=0;j<2;j++){
      if(j==1 && cg>=16) break;
      int c = 48*p + cg + 32*j;
      float4 a = j?a1:a0;
      #pragma unroll
      for(int q=0;q<4;q++){
        int px = pix0 + 4*t4 + q;
        float vv = (q==0)?a.x:(q==1)?a.y:(q==2)?a.z:a.w;
        ot[(size_t)px*Cc + c] = vv + xi[(size_t)px*Cc + c];
      }
    }
  }
}

// ---- K8: (B,HW,C) -> (B,C,HW) tiled transpose ----
__global__ __launch_bounds__(256) void k_outT(const float* __restrict__ ot, float* __restrict__ out){
  __shared__ float tile[64][33];
  int p0=blockIdx.x*64, c0=blockIdx.y*32, b=blockIdx.z;
  int cl=threadIdx.x%32, pl=threadIdx.x/32;
  for(int i=0;i<8;i++){
    int p = pl+i*8;
    tile[p][cl] = ot[((size_t)(b*HW+p0+p))*Cc + c0+cl];
  }
  __syncthreads();
  int pj=threadIdx.x%64, ci=threadIdx.x/64;
  for(int i=0;i<8;i++){
    int c=ci+i*4;
    out[((size_t)(b*Cc+c0+c))*HW + p0+pj] = tile[pj][c];
  }
}

extern "C" void kernel_launch(void* const* d_in, const int* in_sizes, int n_in,
                              void* d_out, int out_size, void* d_ws, size_t ws_size,
                              hipStream_t stream){
  const float* x   = (const float*)d_in[0];
  const float* cw1 = (const float*)d_in[1];
  const float* cw2 = (const float*)d_in[2];
  const float* lng = (const float*)d_in[3];
  const float* lnb = (const float*)d_in[4];
  const float* ipw = (const float*)d_in[5];
  const float* cvw = (const float*)d_in[6];
  const float* cvb = (const float*)d_in[7];
  const float* xpw = (const float*)d_in[8];
  const float* dtw = (const float*)d_in[9];
  const float* dtb = (const float*)d_in[10];
  const float* alg = (const float*)d_in[11];
  const float* ds  = (const float*)d_in[12];
  const float* ong = (const float*)d_in[13];
  const float* onb = (const float*)d_in[14];
  const float* opw = (const float*)d_in[15];
  float* out = (float*)d_out;
  float* ws = (float*)d_ws;

  float* s_   = ws;                          // 384
  float* a_   = s_  + 384;                   // 384
  float* xi_  = a_  + 384;                   // 884736
  float* xc_  = xi_ + 884736;                // 1769472 (reused: hloc+P after conv)
  float* z_   = xc_ + 1769472;               // 1769472
  float* xo_  = z_  + 1769472;               // 1769472
  _Float16* dtT_ = (_Float16*)(xo_ + 1769472);   // 7077888 halves
  _Float16* uT_  = dtT_ + 7077888;               // 3538944 halves
  float* BC_  = (float*)(uT_ + 3538944);     // 1179648 (fused B+C, t-major)
  float* yB_  = BC_ + 1179648;               // 7077888
  float* ot_  = yB_ + 7077888;               // 884736 (reused: Hinit before merge)

  float* hloc_ = xc_;                        // 786432
  float* Pb_   = xc_ + 786432;               // 786432
  float* Hin_  = ot_;                        // 786432

  k_mean  <<<Bn*Cc, 256, 0, stream>>>(x, s_);
  k_ca    <<<1, 384, 0, stream>>>(s_, cw1, cw2, a_);
  k_xca   <<<dim3(HW/64, Cc/32, Bn), 256, 0, stream>>>(x, a_, xi_);
  k_lnproj<<<dim3(Bn*HW/32, 3), 256, 0, stream>>>(xi_, lng, lnb, ipw, xc_, z_);
  k_conv  <<<(Bn*HW*(Dd/4))/256, 256, 0, stream>>>(xc_, cvw, cvb, xo_);
  k_xdbl  <<<Bn*Kk*(Ll/32), 256, 0, stream>>>(xo_, xpw, dtw, dtb, dtT_, uT_, BC_);
  k_scan1 <<<Bn*Kk*NCH*3, 256, 0, stream>>>(dtT_, uT_, BC_, alg, hloc_, Pb_);
  k_comb  <<<(Bn*Kk*Dd*NS)/256, 256, 0, stream>>>(hloc_, Pb_, Hin_);
  k_scan2 <<<Bn*Kk*NCH*3, 256, 0, stream>>>(dtT_, uT_, BC_, alg, ds, Hin_, yB_);
  k_merge <<<Bn*HW/32, 256, 0, stream>>>(yB_, ong, onb, z_, opw, xi_, ot_);
  k_outT  <<<dim3(HW/64, Cc/32, Bn), 256, 0, stream>>>(ot_, out);
}